// Round 3
// baseline (3500.085 us; speedup 1.0000x reference)
//
#include <hip/hip_runtime.h>
#include <math.h>

#define T_STEPS 2048
#define HID     128
#define G4      512   // 4*H

typedef _Float16 half8 __attribute__((ext_vector_type(8)));
typedef float    f32x4 __attribute__((ext_vector_type(4)));

__device__ __forceinline__ float fast_sig(float x) {
    return __fdividef(1.0f, 1.0f + __expf(-x));
}
__device__ __forceinline__ float fast_tanh(float x) {
    return fmaf(2.0f, __fdividef(1.0f, 1.0f + __expf(-2.0f * x)), -1.0f);
}

// ---------------------------------------------------------------------------
// MFMA LSTM recurrence, single live batch element (b = 127).
//
// ROUND 7 (store-drain fix):
//   R6 evidence: spill fixed (VGPR=80, WRITE==hout exactly) but dur pinned
//   at ~2176 cy/step. FETCH = 1024 B/step + weights = RFO on the per-step
//   hout store: each of 8 waves writes 64 B of a 128-B line -> 8 RFO line
//   fetches/step, and __syncthreads' vmcnt(0) drain waits for the store
//   ack (~900 cy, HBM RFO) EVERY STEP. (Round-0 cross-check: its 2-wave
//   full-line store showed FETCH=268 KB = weights only. Consistent.)
//
//   Fix: LDS ring buffer for h rows (64 x 128 f32 = 32 KB); dump 32 rows
//   every 32 steps as fully-coalesced full-line dwordx4 stores. Per-step
//   barrier now drains zero outstanding VMEM (L0) / one 1-step-old L2
//   prefetch (L1). Store ack paid once per 32 steps (~28 cy/step).
//   Everything else unchanged from R6 (isolated A/B on the store theory).
// ---------------------------------------------------------------------------
template<bool IS_L0>
__global__ __launch_bounds__(512)
void lstm_rec_mfma(const float* __restrict__ Whh,   // (512,128) row-major
                   const float* __restrict__ xin,   // L0: x (T,128) ; L1: G (T,512)
                   const float* __restrict__ wih0,  // L0 only (512,)
                   const float* __restrict__ bih,   // L0 only
                   const float* __restrict__ bhh,   // L0 only
                   float* __restrict__ hout)        // (T,128)
{
    const int tid  = threadIdx.x;
    const int wave = tid >> 6;         // 0..7
    const int lane = tid & 63;
    const int quad = lane >> 4;
    const int col  = lane & 15;

    const bool act_lane = (col < 4);
    const int  u = wave * 16 + quad * 4 + col;   // hidden unit (act lanes)

    __shared__ __align__(16) _Float16 h16[2][HID];   // double-buffered h (f16)
    __shared__ __align__(16) float hring[64][HID];   // h history ring (32 KB)
    __shared__ float x_s[T_STEPS];                   // L0: x[t,127] table (8 KB)
    __shared__ char occupancy_pad[22 * 1024];        // total LDS = 64000 B ->
                                                     // 2 WG/CU (RA budget lever)
    ((volatile char*)occupancy_pad)[tid] = 0;        // keep the pad alive

    // afrag[g][kt] = Whh[128*g + wave*16 + col][kt*32 + quad*8 + j]
    half8 afrag[4][4];
    #pragma unroll
    for (int g = 0; g < 4; ++g) {
        const float* row = Whh + (size_t)(128 * g + wave * 16 + col) * HID;
        #pragma unroll
        for (int kt = 0; kt < 4; ++kt) {
            const float4* p = reinterpret_cast<const float4*>(row + kt * 32 + quad * 8);
            float4 lo = p[0], hi = p[1];
            half8 h;
            h[0] = (_Float16)lo.x; h[1] = (_Float16)lo.y;
            h[2] = (_Float16)lo.z; h[3] = (_Float16)lo.w;
            h[4] = (_Float16)hi.x; h[5] = (_Float16)hi.y;
            h[6] = (_Float16)hi.z; h[7] = (_Float16)hi.w;
            afrag[g][kt] = h;
        }
    }

    // L0: per-lane pre-activation constants for THIS lane's unit (8 regs)
    f32x4 bsum4 = {0,0,0,0}, w4 = {0,0,0,0};
    if (IS_L0) {
        if (act_lane) {
            #pragma unroll
            for (int g = 0; g < 4; ++g) {
                bsum4[g] = bih[128 * g + u] + bhh[128 * g + u];
                w4[g]    = wih0[128 * g + u];
            }
        }
        // x table: x[t,127,0] at stride 128
        for (int i = tid; i < T_STEPS; i += 512)
            x_s[i] = xin[(size_t)i * HID + HID - 1];
    }

    // pin weight fragments into AGPRs (MFMA reads A from AGPR directly)
    #pragma unroll
    for (int g = 0; g < 4; ++g)
        #pragma unroll
        for (int kt = 0; kt < 4; ++kt) asm volatile("" : "+a"(afrag[g][kt]));
    if (IS_L0) asm volatile("" : "+v"(bsum4), "+v"(w4));

    // L1: pre-activation pipeline, 4 scalar gate values per act-lane
    f32x4 pre_cur = {0,0,0,0}, pre_nxt = {0,0,0,0};
    if (!IS_L0) {
        if (act_lane) {
            #pragma unroll
            for (int g = 0; g < 4; ++g)
                pre_cur[g] = xin[128 * g + u];     // G[0][gate]
        }
    }

    if (tid < HID) h16[0][tid] = (_Float16)0.0f;
    __syncthreads();

    float c_reg = 0.0f;

    for (int t = 0; t < T_STEPS; ++t) {
        // dump the half-ring filled during the previous 32 steps as
        // fully-coalesced full-line stores (once per 32 steps; the store
        // ack drains at a later barrier, amortized ~28 cy/step)
        if ((t & 31) == 0 && t > 0) {
            const int base = (((t >> 5) & 1) ^ 1) * 32;   // slot half to dump
            const int trow = t - 32;
            #pragma unroll
            for (int i = 0; i < 2; ++i) {
                int id  = i * 512 + tid;      // float4 index in 32x128 block
                int row = id >> 5;            // 0..31
                int c4  = id & 31;
                float4 v = *reinterpret_cast<const float4*>(&hring[base + row][c4 * 4]);
                *reinterpret_cast<float4*>(&hout[(size_t)(trow + row) * HID + c4 * 4]) = v;
            }
        }

        // L1: prefetch next step's 4 pre-activation gates
        const int tn = (t + 1 < T_STEPS) ? t + 1 : t;
        if (!IS_L0) {
            if (act_lane) {
                #pragma unroll
                for (int g = 0; g < 4; ++g)
                    pre_nxt[g] = xin[(size_t)tn * G4 + 128 * g + u];
            }
            asm volatile("" : "+v"(pre_nxt));   // force issue here
        }

        // D = Whh_tile @ h   (16 MFMA/wave, 4 independent accumulator chains)
        f32x4 acc[4] = {};
        #pragma unroll
        for (int kt = 0; kt < 4; ++kt) {
            half8 bfrag = *reinterpret_cast<const half8*>(&h16[t & 1][kt * 32 + quad * 8]);
            #pragma unroll
            for (int g = 0; g < 4; ++g)
                acc[g] = __builtin_amdgcn_mfma_f32_16x16x32_f16(
                             afrag[g][kt], bfrag, acc[g], 0, 0, 0);
        }

        // in-lane gather of this unit's i/f/g/o (static unrolled select)
        float gi = 0.f, gf = 0.f, gg = 0.f, go = 0.f;
        #pragma unroll
        for (int cs = 0; cs < 4; ++cs) {
            if (col == cs) {
                gi = acc[0][cs];
                gf = acc[1][cs];
                gg = acc[2][cs];
                go = acc[3][cs];
            }
        }

        // add pre-activation (bias + input-path contribution)
        f32x4 pre;
        if (IS_L0) {
            const float xv = x_s[t];
            pre = bsum4 + w4 * xv;
        } else {
            pre = pre_cur;
        }
        gi += pre[0]; gf += pre[1]; gg += pre[2]; go += pre[3];

        // activations + in-lane c/h update
        const float ai = fast_sig(gi);
        const float af = fast_sig(gf);
        const float ag = fast_tanh(gg);
        const float ao = fast_sig(go);
        c_reg = fmaf(af, c_reg, ai * ag);
        const float h = ao * fast_tanh(c_reg);

        if (act_lane) {
            h16[(t + 1) & 1][u] = (_Float16)h;
            hring[t & 63][u]    = h;
        }
        if (!IS_L0) pre_cur = pre_nxt;

        __syncthreads();
    }

    // final dump: rows 2016..2047 live in slots 32..63
    {
        #pragma unroll
        for (int i = 0; i < 2; ++i) {
            int id  = i * 512 + tid;
            int row = id >> 5;
            int c4  = id & 31;
            float4 v = *reinterpret_cast<const float4*>(&hring[32 + row][c4 * 4]);
            *reinterpret_cast<float4*>(&hout[(size_t)(T_STEPS - 32 + row) * HID + c4 * 4]) = v;
        }
    }
}

// ---------------------------------------------------------------------------
// C[m,n] = sum_k A[m,k] * W[n,k] + b1[n] (+ b2[n])    K = 128 fixed
// ---------------------------------------------------------------------------
#define BM 64
#define BN 64
__global__ __launch_bounds__(256)
void gemm_bias_kernel(const float* __restrict__ A,   // (M,128)
                      const float* __restrict__ W,   // (N,128)
                      const float* __restrict__ b1,
                      const float* __restrict__ b2,  // may be null
                      float* __restrict__ C,         // (M,N)
                      int M, int N)
{
    __shared__ float Al[128][BM + 4];
    __shared__ float Wl[128][BN + 4];
    const int tid    = threadIdx.x;
    const int m_base = blockIdx.x * BM;
    const int n_base = blockIdx.y * BN;

    {
        const int r  = tid >> 2;          // 0..63
        const int kq = (tid & 3) * 32;    // 0,32,64,96
        const float4* srcA = reinterpret_cast<const float4*>(A + (size_t)(m_base + r) * 128 + kq);
        #pragma unroll
        for (int i = 0; i < 8; ++i) {
            float4 v = srcA[i];
            int k = kq + 4 * i;
            Al[k + 0][r] = v.x; Al[k + 1][r] = v.y; Al[k + 2][r] = v.z; Al[k + 3][r] = v.w;
        }
        const float4* srcW = reinterpret_cast<const float4*>(W + (size_t)(n_base + r) * 128 + kq);
        #pragma unroll
        for (int i = 0; i < 8; ++i) {
            float4 v = srcW[i];
            int k = kq + 4 * i;
            Wl[k + 0][r] = v.x; Wl[k + 1][r] = v.y; Wl[k + 2][r] = v.z; Wl[k + 3][r] = v.w;
        }
    }
    __syncthreads();

    const int tm = (tid & 15) * 4;
    const int tn = (tid >> 4) * 4;
    float acc[4][4] = {};
    #pragma unroll 8
    for (int k = 0; k < 128; ++k) {
        float4 av = *reinterpret_cast<const float4*>(&Al[k][tm]);
        float4 wv = *reinterpret_cast<const float4*>(&Wl[k][tn]);
        acc[0][0] = fmaf(av.x, wv.x, acc[0][0]);
        acc[0][1] = fmaf(av.x, wv.y, acc[0][1]);
        acc[0][2] = fmaf(av.x, wv.z, acc[0][2]);
        acc[0][3] = fmaf(av.x, wv.w, acc[0][3]);
        acc[1][0] = fmaf(av.y, wv.x, acc[1][0]);
        acc[1][1] = fmaf(av.y, wv.y, acc[1][1]);
        acc[1][2] = fmaf(av.y, wv.z, acc[1][2]);
        acc[1][3] = fmaf(av.y, wv.w, acc[1][3]);
        acc[2][0] = fmaf(av.z, wv.x, acc[2][0]);
        acc[2][1] = fmaf(av.z, wv.y, acc[2][1]);
        acc[2][2] = fmaf(av.z, wv.z, acc[2][2]);
        acc[2][3] = fmaf(av.z, wv.w, acc[2][3]);
        acc[3][0] = fmaf(av.w, wv.x, acc[3][0]);
        acc[3][1] = fmaf(av.w, wv.y, acc[3][1]);
        acc[3][2] = fmaf(av.w, wv.z, acc[3][2]);
        acc[3][3] = fmaf(av.w, wv.w, acc[3][3]);
    }

    float bias[4];
    #pragma unroll
    for (int i = 0; i < 4; ++i) {
        int n = n_base + tn + i;
        bias[i] = b1[n] + (b2 ? b2[n] : 0.0f);
    }
    #pragma unroll
    for (int mi = 0; mi < 4; ++mi) {
        float4 o;
        o.x = acc[mi][0] + bias[0];
        o.y = acc[mi][1] + bias[1];
        o.z = acc[mi][2] + bias[2];
        o.w = acc[mi][3] + bias[3];
        *reinterpret_cast<float4*>(C + (size_t)(m_base + tm + mi) * N + n_base + tn) = o;
    }
}

// ---------------------------------------------------------------------------
__global__ __launch_bounds__(512)
void bn_stats_kernel(const float* __restrict__ Z,       // (T,128)
                     const float* __restrict__ gamma,
                     const float* __restrict__ beta,
                     float* __restrict__ scale,
                     float* __restrict__ shift)
{
    const int tid = threadIdx.x;
    const int col = tid & 127;
    const int seg = tid >> 7;     // 0..3
    float s = 0.f, sq = 0.f;
    for (int t = seg * 512; t < (seg + 1) * 512; ++t) {
        float v = Z[(size_t)t * 128 + col];
        s += v;
        sq = fmaf(v, v, sq);
    }
    __shared__ float ps[4][128], pq[4][128];
    ps[seg][col] = s;
    pq[seg][col] = sq;
    __syncthreads();
    if (tid < 128) {
        float sum = ps[0][tid] + ps[1][tid] + ps[2][tid] + ps[3][tid];
        float sqq = pq[0][tid] + pq[1][tid] + pq[2][tid] + pq[3][tid];
        float mean = sum * (1.0f / 2048.0f);
        float var  = sqq * (1.0f / 2048.0f) - mean * mean;
        float sc = gamma[tid] * rsqrtf(var + 1e-5f);
        scale[tid] = sc;
        shift[tid] = beta[tid] - mean * sc;
    }
}

// ---------------------------------------------------------------------------
__global__ __launch_bounds__(512)
void fc2_kernel(const float* __restrict__ Z,      // (T,128)
                const float* __restrict__ scale,
                const float* __restrict__ shift,
                const float* __restrict__ fc2_w,  // (8,128)
                const float* __restrict__ fc2_b,
                float* __restrict__ out)          // (T,8)
{
    const int gid = blockIdx.x * blockDim.x + threadIdx.x;   // 0..16383
    const int o = gid & 7;
    const int t = gid >> 3;

    __shared__ float w_s[8][132];
    __shared__ float sc_s[128], sh_s[128];
    for (int i = threadIdx.x; i < 1024; i += 512) w_s[i >> 7][i & 127] = fc2_w[i];
    if (threadIdx.x < 128) {
        sc_s[threadIdx.x] = scale[threadIdx.x];
        sh_s[threadIdx.x] = shift[threadIdx.x];
    }
    __syncthreads();

    float acc = fc2_b[o];
    const float* zrow = Z + (size_t)t * 128;
    #pragma unroll 4
    for (int k = 0; k < 128; ++k) {
        float zn = fmaf(zrow[k], sc_s[k], sh_s[k]);
        zn = fmaxf(zn, 0.0f);
        acc = fmaf(zn, w_s[o][k], acc);
    }
    out[gid] = acc;
}

// ---------------------------------------------------------------------------
extern "C" void kernel_launch(void* const* d_in, const int* in_sizes, int n_in,
                              void* d_out, int out_size, void* d_ws, size_t ws_size,
                              hipStream_t stream)
{
    const float* x     = (const float*)d_in[0];   // (2048,128,1)
    const float* Wih0  = (const float*)d_in[1];   // (512,1)
    const float* Whh0  = (const float*)d_in[2];   // (512,128)
    const float* bih0  = (const float*)d_in[3];
    const float* bhh0  = (const float*)d_in[4];
    const float* Wih1  = (const float*)d_in[5];   // (512,128)
    const float* Whh1  = (const float*)d_in[6];   // (512,128)
    const float* bih1  = (const float*)d_in[7];
    const float* bhh1  = (const float*)d_in[8];
    const float* fc1_w = (const float*)d_in[9];   // (128,128)
    const float* fc1_b = (const float*)d_in[10];
    const float* gamma = (const float*)d_in[11];
    const float* beta  = (const float*)d_in[12];
    const float* fc2_w = (const float*)d_in[13];  // (8,128)
    const float* fc2_b = (const float*)d_in[14];
    float* out = (float*)d_out;                    // (2048,8) fp32

    float* h1    = (float*)d_ws;            // 2048*128
    float* G     = h1  + T_STEPS * HID;     // 2048*512
    float* h2    = G   + T_STEPS * G4;      // 2048*128
    float* z     = h2  + T_STEPS * HID;     // 2048*128
    float* scale = z   + T_STEPS * HID;     // 128
    float* shift = scale + 128;             // 128

    // K1: layer-0 recurrence (only batch element 127 matters)
    lstm_rec_mfma<true><<<1, 512, 0, stream>>>(Whh0, x, Wih0, bih0, bhh0, h1);

    // K2: layer-1 input GEMM: G[t,:] = h1[t,:] @ Wih1^T + (bih1+bhh1)
    dim3 g2(T_STEPS / BM, G4 / BN);
    gemm_bias_kernel<<<g2, 256, 0, stream>>>(h1, Wih1, bih1, bhh1, G, T_STEPS, G4);

    // K3: layer-1 recurrence consuming precomputed G
    lstm_rec_mfma<false><<<1, 512, 0, stream>>>(Whh1, G, nullptr, nullptr, nullptr, h2);

    // K4a: z = h2 @ fc1^T + fc1_b
    dim3 g4(T_STEPS / BM, HID / BN);
    gemm_bias_kernel<<<g4, 256, 0, stream>>>(h2, fc1_w, fc1_b, nullptr, z, T_STEPS, HID);

    // K4b: batchnorm stats over T axis
    bn_stats_kernel<<<1, 512, 0, stream>>>(z, gamma, beta, scale, shift);

    // K4c: normalize + relu + fc2
    fc2_kernel<<<T_STEPS * 8 / 512, 512, 0, stream>>>(z, scale, shift, fc2_w, fc2_b, out);
}

// Round 5
// 3387.402 us; speedup vs baseline: 1.0333x; 1.0333x over previous
//
#include <hip/hip_runtime.h>
#include <math.h>

#define T_STEPS 2048
#define HID     128
#define G4      512   // 4*H

typedef _Float16 half8 __attribute__((ext_vector_type(8)));
typedef float    f32x4 __attribute__((ext_vector_type(4)));

__device__ __forceinline__ float fast_sig(float x) {
    return __fdividef(1.0f, 1.0f + __expf(-x));
}
__device__ __forceinline__ float fast_tanh(float x) {
    return fmaf(2.0f, __fdividef(1.0f, 1.0f + __expf(-2.0f * x)), -1.0f);
}

// ---------------------------------------------------------------------------
// MFMA LSTM recurrence, single live batch element (b = 127).
//
// ROUND 9 == ROUND 8 resubmit (R8 bench was an infra failure: container
// acquisition failed twice; kernel never ran).
//
// ROUND 8 (pipe-accounting restructure):
//   R6/R7 A/B evidence killed the spill theory AND the store-drain theory
//   (removing all per-step stores changed nothing; FETCH pinned at 2183 KB
//   regardless). Per-step accounting at 2242 cy: MFMA ~620 (fixed floor:
//   128x 16x16x32 f16 GEMV, B-broadcast wastes 15/16 of the pipe and no
//   shape avoids it), LDS ~384 (8 waves x 4 ds_read_b128 x 12 cy - every
//   wave redundantly reads the same h), VALU ~290, serial latency ~400.
//   Waves are barrier-lockstepped -> phases serialize, scale with waves.
//
//   Fix: 4 WAVES (256 thr). Wave owns 32 units = 128 gates = 8 row-tiles
//   x 4 k-tiles = 32 MFMA/wave (per-CU MFMA unchanged, spread 1 wave/SIMD).
//   LDS reads halve (16), VALU/CU ~halves, 4-wave barrier. afrag[8][4] =
//   128 regs pinned to AGPRs ("+a" - proven R6/R7); arch VGPR ~100,
//   unified ~230 < 256 budget at LDS-capped 2 WG/CU (pad -> 64000 B,
//   round-0's empirically-respected lever at 256 thr). Direct full-line
//   128 B/wave stores (R7 proved store drain is free; ring removed).
//
//   acc[r][reg] = gate (r>>1), unit wave*32 + (r&1)*16 + quad*4 + reg,
//   identical across all 16 cols (B broadcast). Lane col<8 activates unit
//   u = wave*32 + (col>>2)*16 + quad*4 + (col&3) via static 8-case select.
// ---------------------------------------------------------------------------
template<bool IS_L0>
__global__ __launch_bounds__(256)
void lstm_rec_mfma(const float* __restrict__ Whh,   // (512,128) row-major
                   const float* __restrict__ xin,   // L0: x (T,128) ; L1: G (T,512)
                   const float* __restrict__ wih0,  // L0 only (512,)
                   const float* __restrict__ bih,   // L0 only
                   const float* __restrict__ bhh,   // L0 only
                   float* __restrict__ hout)        // (T,128)
{
    const int tid  = threadIdx.x;
    const int wave = tid >> 6;         // 0..3
    const int lane = tid & 63;
    const int quad = lane >> 4;
    const int col  = lane & 15;

    const bool act_lane = (col < 8);
    const int  hh = (col >> 2) & 1;    // which 16-half of the wave's 32 units
    const int  rr = col & 3;           // acc register index
    const int  u  = wave * 32 + hh * 16 + quad * 4 + rr;   // hidden unit

    __shared__ __align__(16) _Float16 h16[2][HID];   // double-buffered h (f16)
    __shared__ float x_s[T_STEPS];                   // L0: x[t,127] table (8 KB)
    __shared__ char occupancy_pad[55296];            // total LDS = 64000 B ->
                                                     // 2 WG/CU (RA budget lever)
    ((volatile char*)occupancy_pad)[tid] = 0;        // keep the pad alive

    // afrag[r][kt]: A row = 128*(r>>1) + wave*32 + (r&1)*16 + col,
    //               k     = kt*32 + quad*8 + j
    half8 afrag[8][4];
    #pragma unroll
    for (int r = 0; r < 8; ++r) {
        const float* row = Whh +
            (size_t)(128 * (r >> 1) + wave * 32 + (r & 1) * 16 + col) * HID;
        #pragma unroll
        for (int kt = 0; kt < 4; ++kt) {
            const float4* p = reinterpret_cast<const float4*>(row + kt * 32 + quad * 8);
            float4 lo = p[0], hi = p[1];
            half8 h;
            h[0] = (_Float16)lo.x; h[1] = (_Float16)lo.y;
            h[2] = (_Float16)lo.z; h[3] = (_Float16)lo.w;
            h[4] = (_Float16)hi.x; h[5] = (_Float16)hi.y;
            h[6] = (_Float16)hi.z; h[7] = (_Float16)hi.w;
            afrag[r][kt] = h;
        }
    }

    // L0: per-lane pre-activation constants for THIS lane's unit (8 regs)
    f32x4 bsum4 = {0,0,0,0}, w4 = {0,0,0,0};
    if (IS_L0) {
        if (act_lane) {
            #pragma unroll
            for (int g = 0; g < 4; ++g) {
                bsum4[g] = bih[128 * g + u] + bhh[128 * g + u];
                w4[g]    = wih0[128 * g + u];
            }
        }
        // x table: x[t,127,0] at stride 128
        for (int i = tid; i < T_STEPS; i += 256)
            x_s[i] = xin[(size_t)i * HID + HID - 1];
    }

    // pin weight fragments into AGPRs (MFMA reads A from AGPR directly)
    #pragma unroll
    for (int r = 0; r < 8; ++r)
        #pragma unroll
        for (int kt = 0; kt < 4; ++kt) asm volatile("" : "+a"(afrag[r][kt]));
    if (IS_L0) asm volatile("" : "+v"(bsum4), "+v"(w4));

    // L1: pre-activation pipeline, 4 scalar gate values per act-lane
    f32x4 pre_cur = {0,0,0,0}, pre_nxt = {0,0,0,0};
    if (!IS_L0) {
        if (act_lane) {
            #pragma unroll
            for (int g = 0; g < 4; ++g)
                pre_cur[g] = xin[128 * g + u];     // G[0][gate]
        }
    }

    if (tid < HID) h16[0][tid] = (_Float16)0.0f;
    __syncthreads();

    float c_reg = 0.0f;
    const f32x4 zero4 = {0.f, 0.f, 0.f, 0.f};

    for (int t = 0; t < T_STEPS; ++t) {
        // B fragments: 4 ds_read_b128 (broadcast within quad-groups)
        half8 b0 = *reinterpret_cast<const half8*>(&h16[t & 1][0 * 32 + quad * 8]);
        half8 b1 = *reinterpret_cast<const half8*>(&h16[t & 1][1 * 32 + quad * 8]);
        half8 b2 = *reinterpret_cast<const half8*>(&h16[t & 1][2 * 32 + quad * 8]);
        half8 b3 = *reinterpret_cast<const half8*>(&h16[t & 1][3 * 32 + quad * 8]);

        // L1: prefetch next step's 4 pre-activation gates (issued under MFMA)
        const int tn = (t + 1 < T_STEPS) ? t + 1 : t;
        if (!IS_L0) {
            if (act_lane) {
                #pragma unroll
                for (int g = 0; g < 4; ++g)
                    pre_nxt[g] = xin[(size_t)tn * G4 + 128 * g + u];
            }
            asm volatile("" : "+v"(pre_nxt));   // force issue here
        }

        // D = Whh_tile @ h: 32 MFMA/wave, 8 independent chains, k-chained x4
        f32x4 acc[8];
        #pragma unroll
        for (int r = 0; r < 8; ++r)
            acc[r] = __builtin_amdgcn_mfma_f32_16x16x32_f16(afrag[r][0], b0, zero4, 0, 0, 0);
        #pragma unroll
        for (int r = 0; r < 8; ++r)
            acc[r] = __builtin_amdgcn_mfma_f32_16x16x32_f16(afrag[r][1], b1, acc[r], 0, 0, 0);
        #pragma unroll
        for (int r = 0; r < 8; ++r)
            acc[r] = __builtin_amdgcn_mfma_f32_16x16x32_f16(afrag[r][2], b2, acc[r], 0, 0, 0);
        #pragma unroll
        for (int r = 0; r < 8; ++r)
            acc[r] = __builtin_amdgcn_mfma_f32_16x16x32_f16(afrag[r][3], b3, acc[r], 0, 0, 0);

        // in-lane gather of this unit's i/f/g/o (static unrolled select)
        float gi = 0.f, gf = 0.f, gg = 0.f, go = 0.f;
        #pragma unroll
        for (int cs = 0; cs < 8; ++cs) {
            if (col == cs) {
                const int h2_ = cs >> 2, r2_ = cs & 3;
                gi = acc[0 + h2_][r2_];
                gf = acc[2 + h2_][r2_];
                gg = acc[4 + h2_][r2_];
                go = acc[6 + h2_][r2_];
            }
        }

        // add pre-activation (bias + input-path contribution)
        f32x4 pre;
        if (IS_L0) {
            const float xv = x_s[t];
            pre = bsum4 + w4 * xv;
        } else {
            pre = pre_cur;
        }
        gi += pre[0]; gf += pre[1]; gg += pre[2]; go += pre[3];

        // activations + in-lane c/h update
        const float ai = fast_sig(gi);
        const float af = fast_sig(gf);
        const float ag = fast_tanh(gg);
        const float ao = fast_sig(go);
        c_reg = fmaf(af, c_reg, ai * ag);
        const float h = ao * fast_tanh(c_reg);

        if (act_lane) {
            h16[(t + 1) & 1][u] = (_Float16)h;
            hout[(size_t)t * HID + u] = h;      // 128 B full line per wave
        }
        if (!IS_L0) pre_cur = pre_nxt;

        __syncthreads();
    }
}

// ---------------------------------------------------------------------------
// C[m,n] = sum_k A[m,k] * W[n,k] + b1[n] (+ b2[n])    K = 128 fixed
// ---------------------------------------------------------------------------
#define BM 64
#define BN 64
__global__ __launch_bounds__(256)
void gemm_bias_kernel(const float* __restrict__ A,   // (M,128)
                      const float* __restrict__ W,   // (N,128)
                      const float* __restrict__ b1,
                      const float* __restrict__ b2,  // may be null
                      float* __restrict__ C,         // (M,N)
                      int M, int N)
{
    __shared__ float Al[128][BM + 4];
    __shared__ float Wl[128][BN + 4];
    const int tid    = threadIdx.x;
    const int m_base = blockIdx.x * BM;
    const int n_base = blockIdx.y * BN;

    {
        const int r  = tid >> 2;          // 0..63
        const int kq = (tid & 3) * 32;    // 0,32,64,96
        const float4* srcA = reinterpret_cast<const float4*>(A + (size_t)(m_base + r) * 128 + kq);
        #pragma unroll
        for (int i = 0; i < 8; ++i) {
            float4 v = srcA[i];
            int k = kq + 4 * i;
            Al[k + 0][r] = v.x; Al[k + 1][r] = v.y; Al[k + 2][r] = v.z; Al[k + 3][r] = v.w;
        }
        const float4* srcW = reinterpret_cast<const float4*>(W + (size_t)(n_base + r) * 128 + kq);
        #pragma unroll
        for (int i = 0; i < 8; ++i) {
            float4 v = srcW[i];
            int k = kq + 4 * i;
            Wl[k + 0][r] = v.x; Wl[k + 1][r] = v.y; Wl[k + 2][r] = v.z; Wl[k + 3][r] = v.w;
        }
    }
    __syncthreads();

    const int tm = (tid & 15) * 4;
    const int tn = (tid >> 4) * 4;
    float acc[4][4] = {};
    #pragma unroll 8
    for (int k = 0; k < 128; ++k) {
        float4 av = *reinterpret_cast<const float4*>(&Al[k][tm]);
        float4 wv = *reinterpret_cast<const float4*>(&Wl[k][tn]);
        acc[0][0] = fmaf(av.x, wv.x, acc[0][0]);
        acc[0][1] = fmaf(av.x, wv.y, acc[0][1]);
        acc[0][2] = fmaf(av.x, wv.z, acc[0][2]);
        acc[0][3] = fmaf(av.x, wv.w, acc[0][3]);
        acc[1][0] = fmaf(av.y, wv.x, acc[1][0]);
        acc[1][1] = fmaf(av.y, wv.y, acc[1][1]);
        acc[1][2] = fmaf(av.y, wv.z, acc[1][2]);
        acc[1][3] = fmaf(av.y, wv.w, acc[1][3]);
        acc[2][0] = fmaf(av.z, wv.x, acc[2][0]);
        acc[2][1] = fmaf(av.z, wv.y, acc[2][1]);
        acc[2][2] = fmaf(av.z, wv.z, acc[2][2]);
        acc[2][3] = fmaf(av.z, wv.w, acc[2][3]);
        acc[3][0] = fmaf(av.w, wv.x, acc[3][0]);
        acc[3][1] = fmaf(av.w, wv.y, acc[3][1]);
        acc[3][2] = fmaf(av.w, wv.z, acc[3][2]);
        acc[3][3] = fmaf(av.w, wv.w, acc[3][3]);
    }

    float bias[4];
    #pragma unroll
    for (int i = 0; i < 4; ++i) {
        int n = n_base + tn + i;
        bias[i] = b1[n] + (b2 ? b2[n] : 0.0f);
    }
    #pragma unroll
    for (int mi = 0; mi < 4; ++mi) {
        float4 o;
        o.x = acc[mi][0] + bias[0];
        o.y = acc[mi][1] + bias[1];
        o.z = acc[mi][2] + bias[2];
        o.w = acc[mi][3] + bias[3];
        *reinterpret_cast<float4*>(C + (size_t)(m_base + tm + mi) * N + n_base + tn) = o;
    }
}

// ---------------------------------------------------------------------------
__global__ __launch_bounds__(512)
void bn_stats_kernel(const float* __restrict__ Z,       // (T,128)
                     const float* __restrict__ gamma,
                     const float* __restrict__ beta,
                     float* __restrict__ scale,
                     float* __restrict__ shift)
{
    const int tid = threadIdx.x;
    const int col = tid & 127;
    const int seg = tid >> 7;     // 0..3
    float s = 0.f, sq = 0.f;
    for (int t = seg * 512; t < (seg + 1) * 512; ++t) {
        float v = Z[(size_t)t * 128 + col];
        s += v;
        sq = fmaf(v, v, sq);
    }
    __shared__ float ps[4][128], pq[4][128];
    ps[seg][col] = s;
    pq[seg][col] = sq;
    __syncthreads();
    if (tid < 128) {
        float sum = ps[0][tid] + ps[1][tid] + ps[2][tid] + ps[3][tid];
        float sqq = pq[0][tid] + pq[1][tid] + pq[2][tid] + pq[3][tid];
        float mean = sum * (1.0f / 2048.0f);
        float var  = sqq * (1.0f / 2048.0f) - mean * mean;
        float sc = gamma[tid] * rsqrtf(var + 1e-5f);
        scale[tid] = sc;
        shift[tid] = beta[tid] - mean * sc;
    }
}

// ---------------------------------------------------------------------------
__global__ __launch_bounds__(512)
void fc2_kernel(const float* __restrict__ Z,      // (T,128)
                const float* __restrict__ scale,
                const float* __restrict__ shift,
                const float* __restrict__ fc2_w,  // (8,128)
                const float* __restrict__ fc2_b,
                float* __restrict__ out)          // (T,8)
{
    const int gid = blockIdx.x * blockDim.x + threadIdx.x;   // 0..16383
    const int o = gid & 7;
    const int t = gid >> 3;

    __shared__ float w_s[8][132];
    __shared__ float sc_s[128], sh_s[128];
    for (int i = threadIdx.x; i < 1024; i += 512) w_s[i >> 7][i & 127] = fc2_w[i];
    if (threadIdx.x < 128) {
        sc_s[threadIdx.x] = scale[threadIdx.x];
        sh_s[threadIdx.x] = shift[threadIdx.x];
    }
    __syncthreads();

    float acc = fc2_b[o];
    const float* zrow = Z + (size_t)t * 128;
    #pragma unroll 4
    for (int k = 0; k < 128; ++k) {
        float zn = fmaf(zrow[k], sc_s[k], sh_s[k]);
        zn = fmaxf(zn, 0.0f);
        acc = fmaf(zn, w_s[o][k], acc);
    }
    out[gid] = acc;
}

// ---------------------------------------------------------------------------
extern "C" void kernel_launch(void* const* d_in, const int* in_sizes, int n_in,
                              void* d_out, int out_size, void* d_ws, size_t ws_size,
                              hipStream_t stream)
{
    const float* x     = (const float*)d_in[0];   // (2048,128,1)
    const float* Wih0  = (const float*)d_in[1];   // (512,1)
    const float* Whh0  = (const float*)d_in[2];   // (512,128)
    const float* bih0  = (const float*)d_in[3];
    const float* bhh0  = (const float*)d_in[4];
    const float* Wih1  = (const float*)d_in[5];   // (512,128)
    const float* Whh1  = (const float*)d_in[6];   // (512,128)
    const float* bih1  = (const float*)d_in[7];
    const float* bhh1  = (const float*)d_in[8];
    const float* fc1_w = (const float*)d_in[9];   // (128,128)
    const float* fc1_b = (const float*)d_in[10];
    const float* gamma = (const float*)d_in[11];
    const float* beta  = (const float*)d_in[12];
    const float* fc2_w = (const float*)d_in[13];  // (8,128)
    const float* fc2_b = (const float*)d_in[14];
    float* out = (float*)d_out;                    // (2048,8) fp32

    float* h1    = (float*)d_ws;            // 2048*128
    float* G     = h1  + T_STEPS * HID;     // 2048*512
    float* h2    = G   + T_STEPS * G4;      // 2048*128
    float* z     = h2  + T_STEPS * HID;     // 2048*128
    float* scale = z   + T_STEPS * HID;     // 128
    float* shift = scale + 128;             // 128

    // K1: layer-0 recurrence (only batch element 127 matters)
    lstm_rec_mfma<true><<<1, 256, 0, stream>>>(Whh0, x, Wih0, bih0, bhh0, h1);

    // K2: layer-1 input GEMM: G[t,:] = h1[t,:] @ Wih1^T + (bih1+bhh1)
    dim3 g2(T_STEPS / BM, G4 / BN);
    gemm_bias_kernel<<<g2, 256, 0, stream>>>(h1, Wih1, bih1, bhh1, G, T_STEPS, G4);

    // K3: layer-1 recurrence consuming precomputed G
    lstm_rec_mfma<false><<<1, 256, 0, stream>>>(Whh1, G, nullptr, nullptr, nullptr, h2);

    // K4a: z = h2 @ fc1^T + fc1_b
    dim3 g4(T_STEPS / BM, HID / BN);
    gemm_bias_kernel<<<g4, 256, 0, stream>>>(h2, fc1_w, fc1_b, nullptr, z, T_STEPS, HID);

    // K4b: batchnorm stats over T axis
    bn_stats_kernel<<<1, 512, 0, stream>>>(z, gamma, beta, scale, shift);

    // K4c: normalize + relu + fc2
    fc2_kernel<<<T_STEPS * 8 / 512, 512, 0, stream>>>(z, scale, shift, fc2_w, fc2_b, out);
}

// Round 6
// 2810.689 us; speedup vs baseline: 1.2453x; 1.2052x over previous
//
#include <hip/hip_runtime.h>
#include <math.h>

#define T_STEPS 2048
#define HID     128
#define G4      512   // 4*H
#define CH      16    // pipeline chunk (timesteps)

typedef _Float16 half8 __attribute__((ext_vector_type(8)));
typedef float    f32x4 __attribute__((ext_vector_type(4)));

__device__ __forceinline__ float fast_sig(float x) {
    return __fdividef(1.0f, 1.0f + __expf(-x));
}
__device__ __forceinline__ float fast_tanh(float x) {
    return fmaf(2.0f, __fdividef(1.0f, 1.0f + __expf(-2.0f * x)), -1.0f);
}

// ---------------------------------------------------------------------------
// ROUND 10: FUSED two-layer LSTM pipeline (single kernel).
//
// Evidence to date: per-step time ~2230 cy is invariant to waves (R9), stores
// (R7), spills (R6), barrier count (R5) -> the recurrence step is latency/
// issue-bound and won't shrink. The serial structure (L0 kernel THEN K2 THEN
// L1 kernel) doubles it. Fix: run L1 lagged 2 chunks behind L0 in the SAME
// kernel, overlapping the two recurrences. Waves 0-3 = L0 (R9 structure
// unchanged). Waves 4-7 = L1; its input transform G = Wih1 @ h1 is computed
// on-chip per 16-step chunk as a FULL-16-column MFMA GEMM (h1 chunk columns
// in the B operand -> 2 extra MFMA/wave/step amortized), consuming an LDS
// f16 h1 ring (h1 never touches HBM; K2 eliminated). Wih1 fragments are
// re-read from L2 each chunk (pre-converted f16 by cvt_wih1) to keep L1
// waves at 128 AGPR + ~110 arch < 256-reg budget (8 waves = 2/SIMD).
//
// Schedule (i = 0..2079, superstep s = i/16, phase p = i%16):
//   L0 waves:  step t0 = i (i < 2048): rec-MFMA from h16A, write h16A and
//              h1ring[i%32] (f16).
//   L1 waves:  (a) G-GEMM slice for chunk cg = s-1 (1<=s<=128): 2 MFMA,
//              A = Wih1h frags (global), B = h1ring chunk (s-1)&1,
//              acc chained over 2 phases, written to Gbuf[(s-1)&1].
//              (b) rec step t1 = i-32: pre = Gbuf[(t1/16)&1] + bsum, rec-MFMA
//              from h16B, write h16B and hout2 (full 128-B line per wave).
//   One __syncthreads per step; all rings double-buffered by parity.
// LDS: Gbuf 2x16x516 f32 (66 KB, pad 516 kills bank conflicts) + h1ring
// 32x136 f16 (8.7 KB) + x_s 8 KB + h16A/B 1 KB = 84 KB -> 1 WG/CU,
// 2 waves/EU, 256-reg budget.
// ---------------------------------------------------------------------------
__global__ __launch_bounds__(512)
void lstm_fused(const float* __restrict__ Whh0,     // (512,128)
                const float* __restrict__ Whh1,     // (512,128)
                const _Float16* __restrict__ Wih1h, // (512,128) f16
                const float* __restrict__ x,        // (2048,128)
                const float* __restrict__ wih0,     // (512,)
                const float* __restrict__ bih0,
                const float* __restrict__ bhh0,
                const float* __restrict__ bih1,
                const float* __restrict__ bhh1,
                float* __restrict__ hout2)          // (2048,128)
{
    const int tid  = threadIdx.x;
    const int wave = tid >> 6;         // 0..7
    const int lane = tid & 63;
    const int quad = lane >> 4;
    const int col  = lane & 15;

    const bool isL0 = (wave < 4);
    const int  wgrp = wave & 3;        // wave index within its layer group

    const bool act_lane = (col < 8);
    const int  hh = (col >> 2) & 1;
    const int  rr = col & 3;
    const int  u  = wgrp * 32 + hh * 16 + quad * 4 + rr;  // hidden unit

    __shared__ __align__(16) _Float16 h16A[2][HID];       // L0 h broadcast
    __shared__ __align__(16) _Float16 h16B[2][HID];       // L1 h broadcast
    __shared__ __align__(16) _Float16 h1ring[32][136];    // 2 chunks h1 (pad)
    __shared__ __align__(16) float    Gbuf[2][CH][516];   // 2 chunks G (pad)
    __shared__ float x_s[T_STEPS];                        // x[t,127] table

    // recurrent weight fragments (same indexing both layers):
    // afrag[r][kt]: row = 128*(r>>1) + wgrp*32 + (r&1)*16 + col,
    //               k   = kt*32 + quad*8 + j
    const float* Whh = isL0 ? Whh0 : Whh1;
    half8 afrag[8][4];
    #pragma unroll
    for (int r = 0; r < 8; ++r) {
        const float* row = Whh +
            (size_t)(128 * (r >> 1) + wgrp * 32 + (r & 1) * 16 + col) * HID;
        #pragma unroll
        for (int kt = 0; kt < 4; ++kt) {
            const float4* p = reinterpret_cast<const float4*>(row + kt * 32 + quad * 8);
            float4 lo = p[0], hi = p[1];
            half8 h;
            h[0] = (_Float16)lo.x; h[1] = (_Float16)lo.y;
            h[2] = (_Float16)lo.z; h[3] = (_Float16)lo.w;
            h[4] = (_Float16)hi.x; h[5] = (_Float16)hi.y;
            h[6] = (_Float16)hi.z; h[7] = (_Float16)hi.w;
            afrag[r][kt] = h;
        }
    }

    // per-lane activation constants
    f32x4 bsum4 = {0,0,0,0}, w4 = {0,0,0,0};
    if (act_lane) {
        #pragma unroll
        for (int g = 0; g < 4; ++g) {
            if (isL0) {
                bsum4[g] = bih0[128 * g + u] + bhh0[128 * g + u];
                w4[g]    = wih0[128 * g + u];
            } else {
                bsum4[g] = bih1[128 * g + u] + bhh1[128 * g + u];
            }
        }
    }

    // x table: x[t,127] at stride 128
    for (int i = tid; i < T_STEPS; i += 512)
        x_s[i] = x[(size_t)i * HID + HID - 1];

    // pin weight fragments into AGPRs
    #pragma unroll
    for (int r = 0; r < 8; ++r)
        #pragma unroll
        for (int kt = 0; kt < 4; ++kt) asm volatile("" : "+a"(afrag[r][kt]));
    asm volatile("" : "+v"(bsum4), "+v"(w4));

    if (tid < HID) {
        h16A[0][tid] = (_Float16)0.0f;
        h16B[0][tid] = (_Float16)0.0f;
    }
    __syncthreads();

    float c_reg = 0.0f;
    f32x4 accg  = {0,0,0,0};             // G-GEMM accumulator (L1 waves)
    const f32x4 zero4 = {0.f, 0.f, 0.f, 0.f};

    const int T_TOT = T_STEPS + 2 * CH;  // 2080: 2-chunk pipeline drain

    for (int i = 0; i < T_TOT; ++i) {
        const int s = i >> 4;            // superstep (chunk of L0 time)
        const int p = i & 15;            // phase within superstep

        if (isL0) {
            // =============== L0 recurrence, step t0 = i ===============
            if (i < T_STEPS) {
                half8 b0 = *reinterpret_cast<const half8*>(&h16A[i & 1][ 0 + quad * 8]);
                half8 b1 = *reinterpret_cast<const half8*>(&h16A[i & 1][32 + quad * 8]);
                half8 b2 = *reinterpret_cast<const half8*>(&h16A[i & 1][64 + quad * 8]);
                half8 b3 = *reinterpret_cast<const half8*>(&h16A[i & 1][96 + quad * 8]);

                f32x4 acc[8];
                #pragma unroll
                for (int r = 0; r < 8; ++r)
                    acc[r] = __builtin_amdgcn_mfma_f32_16x16x32_f16(afrag[r][0], b0, zero4, 0, 0, 0);
                #pragma unroll
                for (int r = 0; r < 8; ++r)
                    acc[r] = __builtin_amdgcn_mfma_f32_16x16x32_f16(afrag[r][1], b1, acc[r], 0, 0, 0);
                #pragma unroll
                for (int r = 0; r < 8; ++r)
                    acc[r] = __builtin_amdgcn_mfma_f32_16x16x32_f16(afrag[r][2], b2, acc[r], 0, 0, 0);
                #pragma unroll
                for (int r = 0; r < 8; ++r)
                    acc[r] = __builtin_amdgcn_mfma_f32_16x16x32_f16(afrag[r][3], b3, acc[r], 0, 0, 0);

                float gi = 0.f, gf = 0.f, gg = 0.f, go = 0.f;
                #pragma unroll
                for (int cs = 0; cs < 8; ++cs) {
                    if (col == cs) {
                        const int h2_ = cs >> 2, r2_ = cs & 3;
                        gi = acc[0 + h2_][r2_];
                        gf = acc[2 + h2_][r2_];
                        gg = acc[4 + h2_][r2_];
                        go = acc[6 + h2_][r2_];
                    }
                }
                f32x4 pre = bsum4 + w4 * x_s[i];
                gi += pre[0]; gf += pre[1]; gg += pre[2]; go += pre[3];

                const float ai = fast_sig(gi);
                const float af = fast_sig(gf);
                const float ag = fast_tanh(gg);
                const float ao = fast_sig(go);
                c_reg = fmaf(af, c_reg, ai * ag);
                const float h = ao * fast_tanh(c_reg);

                if (act_lane) {
                    h16A[(i + 1) & 1][u] = (_Float16)h;
                    h1ring[i & 31][u]    = (_Float16)h;   // feeds G-GEMM
                }
            }
        } else {
            // =============== G-GEMM slice: chunk cg = s-1 ===============
            // per wave: 8 m-tiles x 4 k-tiles over 16 phases (2 MFMA/phase);
            // acc spans phases 2m..2m+1, written at odd p.
            half8 wf0, wf1, bg0, bg1;
            const bool do_g = (s >= 1 && s <= T_STEPS / CH);
            const int  cg   = s - 1;
            const int  mt   = p >> 1;
            const int  kt0  = (p & 1) * 2;
            if (do_g) {
                const int gtile = wgrp * 8 + mt;
                const _Float16* wbase =
                    Wih1h + (size_t)(gtile * 16 + col) * HID + quad * 8;
                wf0 = *reinterpret_cast<const half8*>(wbase + kt0 * 32);
                wf1 = *reinterpret_cast<const half8*>(wbase + kt0 * 32 + 32);
                const _Float16* rbase = &h1ring[(cg & 1) * 16 + col][quad * 8];
                bg0 = *reinterpret_cast<const half8*>(rbase + kt0 * 32);
                bg1 = *reinterpret_cast<const half8*>(rbase + kt0 * 32 + 32);
            }

            // =============== L1 recurrence, step t1 = i-32 ===============
            if (i >= 2 * CH) {
                const int t1 = i - 2 * CH;

                half8 b0 = *reinterpret_cast<const half8*>(&h16B[t1 & 1][ 0 + quad * 8]);
                half8 b1 = *reinterpret_cast<const half8*>(&h16B[t1 & 1][32 + quad * 8]);
                half8 b2 = *reinterpret_cast<const half8*>(&h16B[t1 & 1][64 + quad * 8]);
                half8 b3 = *reinterpret_cast<const half8*>(&h16B[t1 & 1][96 + quad * 8]);

                // pre-activation from on-chip G
                f32x4 pre = bsum4;
                if (act_lane) {
                    const float* gr = &Gbuf[(t1 >> 4) & 1][t1 & 15][u];
                    pre[0] += gr[0];
                    pre[1] += gr[128];
                    pre[2] += gr[256];
                    pre[3] += gr[384];
                }

                f32x4 acc[8];
                #pragma unroll
                for (int r = 0; r < 8; ++r)
                    acc[r] = __builtin_amdgcn_mfma_f32_16x16x32_f16(afrag[r][0], b0, zero4, 0, 0, 0);
                #pragma unroll
                for (int r = 0; r < 8; ++r)
                    acc[r] = __builtin_amdgcn_mfma_f32_16x16x32_f16(afrag[r][1], b1, acc[r], 0, 0, 0);
                #pragma unroll
                for (int r = 0; r < 8; ++r)
                    acc[r] = __builtin_amdgcn_mfma_f32_16x16x32_f16(afrag[r][2], b2, acc[r], 0, 0, 0);
                #pragma unroll
                for (int r = 0; r < 8; ++r)
                    acc[r] = __builtin_amdgcn_mfma_f32_16x16x32_f16(afrag[r][3], b3, acc[r], 0, 0, 0);

                // G-GEMM MFMAs ride behind the rec block (loads issued early)
                if (do_g) {
                    if (kt0 == 0) accg = zero4;
                    accg = __builtin_amdgcn_mfma_f32_16x16x32_f16(wf0, bg0, accg, 0, 0, 0);
                    accg = __builtin_amdgcn_mfma_f32_16x16x32_f16(wf1, bg1, accg, 0, 0, 0);
                    if (kt0 == 2) {   // k complete -> write G tile column
                        const int gtile = wgrp * 8 + mt;
                        float* gw = &Gbuf[cg & 1][col][gtile * 16 + quad * 4];
                        *reinterpret_cast<float4*>(gw) =
                            make_float4(accg[0], accg[1], accg[2], accg[3]);
                    }
                }

                float gi = 0.f, gf = 0.f, gg = 0.f, go = 0.f;
                #pragma unroll
                for (int cs = 0; cs < 8; ++cs) {
                    if (col == cs) {
                        const int h2_ = cs >> 2, r2_ = cs & 3;
                        gi = acc[0 + h2_][r2_];
                        gf = acc[2 + h2_][r2_];
                        gg = acc[4 + h2_][r2_];
                        go = acc[6 + h2_][r2_];
                    }
                }
                gi += pre[0]; gf += pre[1]; gg += pre[2]; go += pre[3];

                const float ai = fast_sig(gi);
                const float af = fast_sig(gf);
                const float ag = fast_tanh(gg);
                const float ao = fast_sig(go);
                c_reg = fmaf(af, c_reg, ai * ag);
                const float h = ao * fast_tanh(c_reg);

                if (act_lane) {
                    h16B[(t1 + 1) & 1][u] = (_Float16)h;
                    hout2[(size_t)t1 * HID + u] = h;   // 128-B line per wave
                }
            } else if (do_g) {
                // fill phase (i in [16,32)): G-GEMM only
                if (kt0 == 0) accg = zero4;
                accg = __builtin_amdgcn_mfma_f32_16x16x32_f16(wf0, bg0, accg, 0, 0, 0);
                accg = __builtin_amdgcn_mfma_f32_16x16x32_f16(wf1, bg1, accg, 0, 0, 0);
                if (kt0 == 2) {
                    const int gtile = wgrp * 8 + mt;
                    float* gw = &Gbuf[cg & 1][col][gtile * 16 + quad * 4];
                    *reinterpret_cast<float4*>(gw) =
                        make_float4(accg[0], accg[1], accg[2], accg[3]);
                }
            }
        }

        __syncthreads();
    }
}

// ---------------------------------------------------------------------------
__global__ __launch_bounds__(256)
void cvt_wih1(const float* __restrict__ w, _Float16* __restrict__ o)
{
    const int i = blockIdx.x * 256 + threadIdx.x;   // 65536 elems
    o[i] = (_Float16)w[i];
}

// ---------------------------------------------------------------------------
// C[m,n] = sum_k A[m,k] * W[n,k] + b1[n] (+ b2[n])    K = 128 fixed
// ---------------------------------------------------------------------------
#define BM 64
#define BN 64
__global__ __launch_bounds__(256)
void gemm_bias_kernel(const float* __restrict__ A,   // (M,128)
                      const float* __restrict__ W,   // (N,128)
                      const float* __restrict__ b1,
                      const float* __restrict__ b2,  // may be null
                      float* __restrict__ C,         // (M,N)
                      int M, int N)
{
    __shared__ float Al[128][BM + 4];
    __shared__ float Wl[128][BN + 4];
    const int tid    = threadIdx.x;
    const int m_base = blockIdx.x * BM;
    const int n_base = blockIdx.y * BN;

    {
        const int r  = tid >> 2;          // 0..63
        const int kq = (tid & 3) * 32;    // 0,32,64,96
        const float4* srcA = reinterpret_cast<const float4*>(A + (size_t)(m_base + r) * 128 + kq);
        #pragma unroll
        for (int i = 0; i < 8; ++i) {
            float4 v = srcA[i];
            int k = kq + 4 * i;
            Al[k + 0][r] = v.x; Al[k + 1][r] = v.y; Al[k + 2][r] = v.z; Al[k + 3][r] = v.w;
        }
        const float4* srcW = reinterpret_cast<const float4*>(W + (size_t)(n_base + r) * 128 + kq);
        #pragma unroll
        for (int i = 0; i < 8; ++i) {
            float4 v = srcW[i];
            int k = kq + 4 * i;
            Wl[k + 0][r] = v.x; Wl[k + 1][r] = v.y; Wl[k + 2][r] = v.z; Wl[k + 3][r] = v.w;
        }
    }
    __syncthreads();

    const int tm = (tid & 15) * 4;
    const int tn = (tid >> 4) * 4;
    float acc[4][4] = {};
    #pragma unroll 8
    for (int k = 0; k < 128; ++k) {
        float4 av = *reinterpret_cast<const float4*>(&Al[k][tm]);
        float4 wv = *reinterpret_cast<const float4*>(&Wl[k][tn]);
        acc[0][0] = fmaf(av.x, wv.x, acc[0][0]);
        acc[0][1] = fmaf(av.x, wv.y, acc[0][1]);
        acc[0][2] = fmaf(av.x, wv.z, acc[0][2]);
        acc[0][3] = fmaf(av.x, wv.w, acc[0][3]);
        acc[1][0] = fmaf(av.y, wv.x, acc[1][0]);
        acc[1][1] = fmaf(av.y, wv.y, acc[1][1]);
        acc[1][2] = fmaf(av.y, wv.z, acc[1][2]);
        acc[1][3] = fmaf(av.y, wv.w, acc[1][3]);
        acc[2][0] = fmaf(av.z, wv.x, acc[2][0]);
        acc[2][1] = fmaf(av.z, wv.y, acc[2][1]);
        acc[2][2] = fmaf(av.z, wv.z, acc[2][2]);
        acc[2][3] = fmaf(av.z, wv.w, acc[2][3]);
        acc[3][0] = fmaf(av.w, wv.x, acc[3][0]);
        acc[3][1] = fmaf(av.w, wv.y, acc[3][1]);
        acc[3][2] = fmaf(av.w, wv.z, acc[3][2]);
        acc[3][3] = fmaf(av.w, wv.w, acc[3][3]);
    }

    float bias[4];
    #pragma unroll
    for (int i = 0; i < 4; ++i) {
        int n = n_base + tn + i;
        bias[i] = b1[n] + (b2 ? b2[n] : 0.0f);
    }
    #pragma unroll
    for (int mi = 0; mi < 4; ++mi) {
        float4 o;
        o.x = acc[mi][0] + bias[0];
        o.y = acc[mi][1] + bias[1];
        o.z = acc[mi][2] + bias[2];
        o.w = acc[mi][3] + bias[3];
        *reinterpret_cast<float4*>(C + (size_t)(m_base + tm + mi) * N + n_base + tn) = o;
    }
}

// ---------------------------------------------------------------------------
__global__ __launch_bounds__(512)
void bn_stats_kernel(const float* __restrict__ Z,       // (T,128)
                     const float* __restrict__ gamma,
                     const float* __restrict__ beta,
                     float* __restrict__ scale,
                     float* __restrict__ shift)
{
    const int tid = threadIdx.x;
    const int col = tid & 127;
    const int seg = tid >> 7;     // 0..3
    float s = 0.f, sq = 0.f;
    for (int t = seg * 512; t < (seg + 1) * 512; ++t) {
        float v = Z[(size_t)t * 128 + col];
        s += v;
        sq = fmaf(v, v, sq);
    }
    __shared__ float ps[4][128], pq[4][128];
    ps[seg][col] = s;
    pq[seg][col] = sq;
    __syncthreads();
    if (tid < 128) {
        float sum = ps[0][tid] + ps[1][tid] + ps[2][tid] + ps[3][tid];
        float sqq = pq[0][tid] + pq[1][tid] + pq[2][tid] + pq[3][tid];
        float mean = sum * (1.0f / 2048.0f);
        float var  = sqq * (1.0f / 2048.0f) - mean * mean;
        float sc = gamma[tid] * rsqrtf(var + 1e-5f);
        scale[tid] = sc;
        shift[tid] = beta[tid] - mean * sc;
    }
}

// ---------------------------------------------------------------------------
__global__ __launch_bounds__(512)
void fc2_kernel(const float* __restrict__ Z,      // (T,128)
                const float* __restrict__ scale,
                const float* __restrict__ shift,
                const float* __restrict__ fc2_w,  // (8,128)
                const float* __restrict__ fc2_b,
                float* __restrict__ out)          // (T,8)
{
    const int gid = blockIdx.x * blockDim.x + threadIdx.x;   // 0..16383
    const int o = gid & 7;
    const int t = gid >> 3;

    __shared__ float w_s[8][132];
    __shared__ float sc_s[128], sh_s[128];
    for (int i = threadIdx.x; i < 1024; i += 512) w_s[i >> 7][i & 127] = fc2_w[i];
    if (threadIdx.x < 128) {
        sc_s[threadIdx.x] = scale[threadIdx.x];
        sh_s[threadIdx.x] = shift[threadIdx.x];
    }
    __syncthreads();

    float acc = fc2_b[o];
    const float* zrow = Z + (size_t)t * 128;
    #pragma unroll 4
    for (int k = 0; k < 128; ++k) {
        float zn = fmaf(zrow[k], sc_s[k], sh_s[k]);
        zn = fmaxf(zn, 0.0f);
        acc = fmaf(zn, w_s[o][k], acc);
    }
    out[gid] = acc;
}

// ---------------------------------------------------------------------------
extern "C" void kernel_launch(void* const* d_in, const int* in_sizes, int n_in,
                              void* d_out, int out_size, void* d_ws, size_t ws_size,
                              hipStream_t stream)
{
    const float* x     = (const float*)d_in[0];   // (2048,128,1)
    const float* Wih0  = (const float*)d_in[1];   // (512,1)
    const float* Whh0  = (const float*)d_in[2];   // (512,128)
    const float* bih0  = (const float*)d_in[3];
    const float* bhh0  = (const float*)d_in[4];
    const float* Wih1  = (const float*)d_in[5];   // (512,128)
    const float* Whh1  = (const float*)d_in[6];   // (512,128)
    const float* bih1  = (const float*)d_in[7];
    const float* bhh1  = (const float*)d_in[8];
    const float* fc1_w = (const float*)d_in[9];   // (128,128)
    const float* fc1_b = (const float*)d_in[10];
    const float* gamma = (const float*)d_in[11];
    const float* beta  = (const float*)d_in[12];
    const float* fc2_w = (const float*)d_in[13];  // (8,128)
    const float* fc2_b = (const float*)d_in[14];
    float* out = (float*)d_out;                    // (2048,8) fp32

    _Float16* wih1h = (_Float16*)d_ws;                    // 512*128 f16 = 128 KB
    float* h2    = (float*)d_ws + 32768;                  // 2048*128
    float* z     = h2 + T_STEPS * HID;                    // 2048*128
    float* scale = z  + T_STEPS * HID;                    // 128
    float* shift = scale + 128;                           // 128

    // K0: Wih1 -> f16 (A-fragments for the on-chip G-GEMM)
    cvt_wih1<<<256, 256, 0, stream>>>(Wih1, wih1h);

    // K1: fused two-layer recurrence pipeline (h1 stays on-chip)
    lstm_fused<<<1, 512, 0, stream>>>(Whh0, Whh1, wih1h, x, Wih0,
                                      bih0, bhh0, bih1, bhh1, h2);

    // K4a: z = h2 @ fc1^T + fc1_b
    dim3 g4(T_STEPS / BM, HID / BN);
    gemm_bias_kernel<<<g4, 256, 0, stream>>>(h2, fc1_w, fc1_b, nullptr, z, T_STEPS, HID);

    // K4b: batchnorm stats over T axis
    bn_stats_kernel<<<1, 512, 0, stream>>>(z, gamma, beta, scale, shift);

    // K4c: normalize + relu + fc2
    fc2_kernel<<<T_STEPS * 8 / 512, 512, 0, stream>>>(z, scale, shift, fc2_w, fc2_b, out);
}

// Round 7
// 2228.977 us; speedup vs baseline: 1.5703x; 1.2610x over previous
//
#include <hip/hip_runtime.h>
#include <math.h>

#define T_STEPS 2048
#define HID     128
#define G4      512   // 4*H
#define CH      16    // pipeline chunk (timesteps)
#define NCHUNK  (T_STEPS / CH)

typedef _Float16 half8 __attribute__((ext_vector_type(8)));
typedef float    f32x4 __attribute__((ext_vector_type(4)));

__device__ __forceinline__ float fast_sig(float x) {
    return __fdividef(1.0f, 1.0f + __expf(-x));
}
__device__ __forceinline__ float fast_tanh(float x) {
    return fmaf(2.0f, __fdividef(1.0f, 1.0f + __expf(-2.0f * x)), -1.0f);
}

// ---------------------------------------------------------------------------
// ROUND 11: 2-CU layer pipeline.
//
// R10 post-mortem: fusion won (3387->2811) but per-step rose 2233->3218 cy:
// the single-CU barrier lockstepped L0-waves and L1-waves, so L1's extra G
// work (global Wih1 loads, G-MFMAs, Gbuf IO, 32 conflicts/step) stacked onto
// every step instead of hiding. R9 measured a 4-wave single-layer step at
// 930 ns on its own CU -- with stall slack.
//
// This round: one kernel, grid=2, one block per CU.
//   Block 0 (L0): exact R9 recurrence; writes h1 as f16 to global; after the
//     barrier closing each 16-step chunk, tid0 releases flags[chunk] with
//     __hip_atomic_store(RELEASE, AGENT) (cross-XCD coherent point; the
//     barrier's vmcnt(0) drain has already pushed all waves' h1 stores to L2,
//     and the release writes back L2).
//   Block 1 (L1): R9 recurrence + R10's on-chip G-GEMM, self-paced:
//     at phase 0 of chunk ct it acquires flags[ct+1] (per-wave lane-0 spin,
//     ACQUIRE/AGENT -> cache invalidate), stages the 4 KB h1 chunk into LDS
//     (one half8 per thread), then computes G(ct+1) as 8 background slices
//     (phases 1..8, 4 chained MFMA each) from AGPR-resident Wih1 fragments
//     -- zero per-step global loads. Rec step reads Gbuf[ct&1].
//   Each block has its own barrier and own ~930ns pace; G work fills block-1
//   stall slots. Lag = 32 steps.
// Occupancy/RA: LDS = 83.5 KB -> 1 WG/CU -> 4 waves = 1 wave/EU -> 512-reg
// budget; demand = 192 AGPR (afrag 128 + wfrag 64) + ~110 arch. No pad
// needed. Flags zeroed per launch by hipMemsetAsync (graph-capturable).
// ---------------------------------------------------------------------------
__global__ __launch_bounds__(256)
void lstm_pipe(const float* __restrict__ Whh0,   // (512,128)
               const float* __restrict__ Whh1,   // (512,128)
               const float* __restrict__ Wih1,   // (512,128)
               const float* __restrict__ x,      // (2048,128)
               const float* __restrict__ wih0,   // (512,)
               const float* __restrict__ bih0,
               const float* __restrict__ bhh0,
               const float* __restrict__ bih1,
               const float* __restrict__ bhh1,
               unsigned int* __restrict__ flags, // (128,) zeroed per launch
               _Float16* __restrict__ h1h,       // (2048,128) f16
               float* __restrict__ hout2)        // (2048,128) f32
{
    const int tid  = threadIdx.x;
    const int wave = tid >> 6;         // 0..3
    const int lane = tid & 63;
    const int quad = lane >> 4;
    const int col  = lane & 15;
    const bool isL0 = (blockIdx.x == 0);

    const bool act_lane = (col < 8);
    const int  hh = (col >> 2) & 1;
    const int  rr = col & 3;
    const int  u  = wave * 32 + hh * 16 + quad * 4 + rr;   // hidden unit

    __shared__ __align__(16) _Float16 h16[2][HID];       // broadcast h (dbuf)
    __shared__ __align__(16) _Float16 h1s[2][CH][136];   // L1: staged h1 chunks
    __shared__ __align__(16) float    Gbuf[2][CH][516];  // L1: G chunks (66 KB)
    __shared__ float x_s[T_STEPS];                       // L0: x[t,127] table
    // total LDS = 512 + 8704 + 66048 + 8192 = 83456 B > 80 KB -> 1 WG/CU

    // recurrent weight fragments (R9 mapping, both layers):
    // afrag[r][kt]: row = 128*(r>>1) + wave*32 + (r&1)*16 + col, k = kt*32+quad*8
    const float* Whh = isL0 ? Whh0 : Whh1;
    half8 afrag[8][4];
    #pragma unroll
    for (int r = 0; r < 8; ++r) {
        const float* row = Whh +
            (size_t)(128 * (r >> 1) + wave * 32 + (r & 1) * 16 + col) * HID;
        #pragma unroll
        for (int kt = 0; kt < 4; ++kt) {
            const float4* p = reinterpret_cast<const float4*>(row + kt * 32 + quad * 8);
            float4 lo = p[0], hi = p[1];
            half8 h;
            h[0] = (_Float16)lo.x; h[1] = (_Float16)lo.y;
            h[2] = (_Float16)lo.z; h[3] = (_Float16)lo.w;
            h[4] = (_Float16)hi.x; h[5] = (_Float16)hi.y;
            h[6] = (_Float16)hi.z; h[7] = (_Float16)hi.w;
            afrag[r][kt] = h;
        }
    }
    #pragma unroll
    for (int r = 0; r < 8; ++r)
        #pragma unroll
        for (int kt = 0; kt < 4; ++kt) asm volatile("" : "+a"(afrag[r][kt]));

    // per-lane activation constants
    f32x4 bsum4 = {0,0,0,0}, w4 = {0,0,0,0};
    if (act_lane) {
        #pragma unroll
        for (int g = 0; g < 4; ++g) {
            if (isL0) {
                bsum4[g] = bih0[128 * g + u] + bhh0[128 * g + u];
                w4[g]    = wih0[128 * g + u];
            } else {
                bsum4[g] = bih1[128 * g + u] + bhh1[128 * g + u];
            }
        }
    }
    asm volatile("" : "+v"(bsum4), "+v"(w4));

    if (isL0) {
        for (int i = tid; i < T_STEPS; i += 256)
            x_s[i] = x[(size_t)i * HID + HID - 1];
    }

    if (tid < HID) h16[0][tid] = (_Float16)0.0f;
    __syncthreads();

    float c_reg = 0.0f;
    const f32x4 zero4 = {0.f, 0.f, 0.f, 0.f};

    if (isL0) {
        // ================= block 0: layer-0 recurrence =================
        for (int t = 0; t < T_STEPS; ++t) {
            half8 b0 = *reinterpret_cast<const half8*>(&h16[t & 1][ 0 + quad * 8]);
            half8 b1 = *reinterpret_cast<const half8*>(&h16[t & 1][32 + quad * 8]);
            half8 b2 = *reinterpret_cast<const half8*>(&h16[t & 1][64 + quad * 8]);
            half8 b3 = *reinterpret_cast<const half8*>(&h16[t & 1][96 + quad * 8]);

            f32x4 acc[8];
            #pragma unroll
            for (int r = 0; r < 8; ++r)
                acc[r] = __builtin_amdgcn_mfma_f32_16x16x32_f16(afrag[r][0], b0, zero4, 0, 0, 0);
            #pragma unroll
            for (int r = 0; r < 8; ++r)
                acc[r] = __builtin_amdgcn_mfma_f32_16x16x32_f16(afrag[r][1], b1, acc[r], 0, 0, 0);
            #pragma unroll
            for (int r = 0; r < 8; ++r)
                acc[r] = __builtin_amdgcn_mfma_f32_16x16x32_f16(afrag[r][2], b2, acc[r], 0, 0, 0);
            #pragma unroll
            for (int r = 0; r < 8; ++r)
                acc[r] = __builtin_amdgcn_mfma_f32_16x16x32_f16(afrag[r][3], b3, acc[r], 0, 0, 0);

            float gi = 0.f, gf = 0.f, gg = 0.f, go = 0.f;
            #pragma unroll
            for (int cs = 0; cs < 8; ++cs) {
                if (col == cs) {
                    const int h2_ = cs >> 2, r2_ = cs & 3;
                    gi = acc[0 + h2_][r2_];
                    gf = acc[2 + h2_][r2_];
                    gg = acc[4 + h2_][r2_];
                    go = acc[6 + h2_][r2_];
                }
            }
            f32x4 pre = bsum4 + w4 * x_s[t];
            gi += pre[0]; gf += pre[1]; gg += pre[2]; go += pre[3];

            const float ai = fast_sig(gi);
            const float af = fast_sig(gf);
            const float ag = fast_tanh(gg);
            const float ao = fast_sig(go);
            c_reg = fmaf(af, c_reg, ai * ag);
            const float h = ao * fast_tanh(c_reg);

            if (act_lane) {
                const _Float16 hf = (_Float16)h;
                h16[(t + 1) & 1][u] = hf;
                h1h[(size_t)t * HID + u] = hf;   // 64 B contiguous per wave
            }
            __syncthreads();   // vmcnt(0) drain -> all h1h stores in L2

            if ((t & 15) == 15 && tid == 0)
                __hip_atomic_store(&flags[t >> 4], 1u,
                                   __ATOMIC_RELEASE, __HIP_MEMORY_SCOPE_AGENT);
        }
    } else {
        // ================= block 1: layer-1 + on-chip G =================
        // Wih1 fragments resident in AGPRs: wfrag[mt][kt],
        // A-row = (wave*8+mt)*16 + col, k = kt*32 + quad*8
        half8 wfrag[8][4];
        #pragma unroll
        for (int mt = 0; mt < 8; ++mt) {
            const float* row = Wih1 + (size_t)((wave * 8 + mt) * 16 + col) * HID;
            #pragma unroll
            for (int kt = 0; kt < 4; ++kt) {
                const float4* p = reinterpret_cast<const float4*>(row + kt * 32 + quad * 8);
                float4 lo = p[0], hi = p[1];
                half8 h;
                h[0] = (_Float16)lo.x; h[1] = (_Float16)lo.y;
                h[2] = (_Float16)lo.z; h[3] = (_Float16)lo.w;
                h[4] = (_Float16)hi.x; h[5] = (_Float16)hi.y;
                h[6] = (_Float16)hi.z; h[7] = (_Float16)hi.w;
                wfrag[mt][kt] = h;
            }
        }
        #pragma unroll
        for (int mt = 0; mt < 8; ++mt)
            #pragma unroll
            for (int kt = 0; kt < 4; ++kt) asm volatile("" : "+a"(wfrag[mt][kt]));

        // ---- prologue: chunk 0 -> h1s[0] -> Gbuf[0] ----
        if (lane == 0) {
            while (__hip_atomic_load(&flags[0],
                       __ATOMIC_ACQUIRE, __HIP_MEMORY_SCOPE_AGENT) == 0u)
                __builtin_amdgcn_s_sleep(2);
        }
        {
            const int row = tid >> 4, c16 = tid & 15;
            half8 v = *reinterpret_cast<const half8*>(
                h1h + (size_t)row * HID + c16 * 8);
            *reinterpret_cast<half8*>(&h1s[0][row][c16 * 8]) = v;
        }
        __syncthreads();
        #pragma unroll
        for (int mt = 0; mt < 8; ++mt) {
            f32x4 ag = zero4;
            #pragma unroll
            for (int kt = 0; kt < 4; ++kt) {
                half8 bg = *reinterpret_cast<const half8*>(
                    &h1s[0][col][kt * 32 + quad * 8]);
                ag = __builtin_amdgcn_mfma_f32_16x16x32_f16(wfrag[mt][kt], bg, ag, 0, 0, 0);
            }
            *reinterpret_cast<float4*>(&Gbuf[0][col][(wave * 8 + mt) * 16 + quad * 4]) =
                make_float4(ag[0], ag[1], ag[2], ag[3]);
        }
        __syncthreads();

        // ---- main loop ----
        for (int j = 0; j < T_STEPS; ++j) {
            const int p  = j & 15;
            const int ct = j >> 4;
            const int cn = ct + 1;

            // phase 0: acquire + stage next chunk
            if (p == 0 && cn < NCHUNK) {
                if (lane == 0) {
                    while (__hip_atomic_load(&flags[cn],
                               __ATOMIC_ACQUIRE, __HIP_MEMORY_SCOPE_AGENT) == 0u)
                        __builtin_amdgcn_s_sleep(2);
                }
                const int row = tid >> 4, c16 = tid & 15;
                half8 v = *reinterpret_cast<const half8*>(
                    h1h + (size_t)(cn * CH + row) * HID + c16 * 8);
                *reinterpret_cast<half8*>(&h1s[cn & 1][row][c16 * 8]) = v;
            }

            // phases 1..8: one G slice each (static mt -> no dynamic reg index)
            #pragma unroll
            for (int mt = 0; mt < 8; ++mt) {
                if (p == mt + 1 && cn < NCHUNK) {
                    f32x4 ag = zero4;
                    #pragma unroll
                    for (int kt = 0; kt < 4; ++kt) {
                        half8 bg = *reinterpret_cast<const half8*>(
                            &h1s[cn & 1][col][kt * 32 + quad * 8]);
                        ag = __builtin_amdgcn_mfma_f32_16x16x32_f16(wfrag[mt][kt], bg, ag, 0, 0, 0);
                    }
                    *reinterpret_cast<float4*>(
                        &Gbuf[cn & 1][col][(wave * 8 + mt) * 16 + quad * 4]) =
                        make_float4(ag[0], ag[1], ag[2], ag[3]);
                }
            }

            // recurrence step j
            half8 b0 = *reinterpret_cast<const half8*>(&h16[j & 1][ 0 + quad * 8]);
            half8 b1 = *reinterpret_cast<const half8*>(&h16[j & 1][32 + quad * 8]);
            half8 b2 = *reinterpret_cast<const half8*>(&h16[j & 1][64 + quad * 8]);
            half8 b3 = *reinterpret_cast<const half8*>(&h16[j & 1][96 + quad * 8]);

            f32x4 pre = bsum4;
            if (act_lane) {
                const float* gr = &Gbuf[ct & 1][p][u];
                pre[0] += gr[0];
                pre[1] += gr[128];
                pre[2] += gr[256];
                pre[3] += gr[384];
            }

            f32x4 acc[8];
            #pragma unroll
            for (int r = 0; r < 8; ++r)
                acc[r] = __builtin_amdgcn_mfma_f32_16x16x32_f16(afrag[r][0], b0, zero4, 0, 0, 0);
            #pragma unroll
            for (int r = 0; r < 8; ++r)
                acc[r] = __builtin_amdgcn_mfma_f32_16x16x32_f16(afrag[r][1], b1, acc[r], 0, 0, 0);
            #pragma unroll
            for (int r = 0; r < 8; ++r)
                acc[r] = __builtin_amdgcn_mfma_f32_16x16x32_f16(afrag[r][2], b2, acc[r], 0, 0, 0);
            #pragma unroll
            for (int r = 0; r < 8; ++r)
                acc[r] = __builtin_amdgcn_mfma_f32_16x16x32_f16(afrag[r][3], b3, acc[r], 0, 0, 0);

            float gi = 0.f, gf = 0.f, gg = 0.f, go = 0.f;
            #pragma unroll
            for (int cs = 0; cs < 8; ++cs) {
                if (col == cs) {
                    const int h2_ = cs >> 2, r2_ = cs & 3;
                    gi = acc[0 + h2_][r2_];
                    gf = acc[2 + h2_][r2_];
                    gg = acc[4 + h2_][r2_];
                    go = acc[6 + h2_][r2_];
                }
            }
            gi += pre[0]; gf += pre[1]; gg += pre[2]; go += pre[3];

            const float ai = fast_sig(gi);
            const float af = fast_sig(gf);
            const float ag = fast_tanh(gg);
            const float ao = fast_sig(go);
            c_reg = fmaf(af, c_reg, ai * ag);
            const float h = ao * fast_tanh(c_reg);

            if (act_lane) {
                h16[(j + 1) & 1][u] = (_Float16)h;
                hout2[(size_t)j * HID + u] = h;
            }
            __syncthreads();
        }
    }
}

// ---------------------------------------------------------------------------
// C[m,n] = sum_k A[m,k] * W[n,k] + b1[n] (+ b2[n])    K = 128 fixed
// ---------------------------------------------------------------------------
#define BM 64
#define BN 64
__global__ __launch_bounds__(256)
void gemm_bias_kernel(const float* __restrict__ A,   // (M,128)
                      const float* __restrict__ W,   // (N,128)
                      const float* __restrict__ b1,
                      const float* __restrict__ b2,  // may be null
                      float* __restrict__ C,         // (M,N)
                      int M, int N)
{
    __shared__ float Al[128][BM + 4];
    __shared__ float Wl[128][BN + 4];
    const int tid    = threadIdx.x;
    const int m_base = blockIdx.x * BM;
    const int n_base = blockIdx.y * BN;

    {
        const int r  = tid >> 2;          // 0..63
        const int kq = (tid & 3) * 32;    // 0,32,64,96
        const float4* srcA = reinterpret_cast<const float4*>(A + (size_t)(m_base + r) * 128 + kq);
        #pragma unroll
        for (int i = 0; i < 8; ++i) {
            float4 v = srcA[i];
            int k = kq + 4 * i;
            Al[k + 0][r] = v.x; Al[k + 1][r] = v.y; Al[k + 2][r] = v.z; Al[k + 3][r] = v.w;
        }
        const float4* srcW = reinterpret_cast<const float4*>(W + (size_t)(n_base + r) * 128 + kq);
        #pragma unroll
        for (int i = 0; i < 8; ++i) {
            float4 v = srcW[i];
            int k = kq + 4 * i;
            Wl[k + 0][r] = v.x; Wl[k + 1][r] = v.y; Wl[k + 2][r] = v.z; Wl[k + 3][r] = v.w;
        }
    }
    __syncthreads();

    const int tm = (tid & 15) * 4;
    const int tn = (tid >> 4) * 4;
    float acc[4][4] = {};
    #pragma unroll 8
    for (int k = 0; k < 128; ++k) {
        float4 av = *reinterpret_cast<const float4*>(&Al[k][tm]);
        float4 wv = *reinterpret_cast<const float4*>(&Wl[k][tn]);
        acc[0][0] = fmaf(av.x, wv.x, acc[0][0]);
        acc[0][1] = fmaf(av.x, wv.y, acc[0][1]);
        acc[0][2] = fmaf(av.x, wv.z, acc[0][2]);
        acc[0][3] = fmaf(av.x, wv.w, acc[0][3]);
        acc[1][0] = fmaf(av.y, wv.x, acc[1][0]);
        acc[1][1] = fmaf(av.y, wv.y, acc[1][1]);
        acc[1][2] = fmaf(av.y, wv.z, acc[1][2]);
        acc[1][3] = fmaf(av.y, wv.w, acc[1][3]);
        acc[2][0] = fmaf(av.z, wv.x, acc[2][0]);
        acc[2][1] = fmaf(av.z, wv.y, acc[2][1]);
        acc[2][2] = fmaf(av.z, wv.z, acc[2][2]);
        acc[2][3] = fmaf(av.z, wv.w, acc[2][3]);
        acc[3][0] = fmaf(av.w, wv.x, acc[3][0]);
        acc[3][1] = fmaf(av.w, wv.y, acc[3][1]);
        acc[3][2] = fmaf(av.w, wv.z, acc[3][2]);
        acc[3][3] = fmaf(av.w, wv.w, acc[3][3]);
    }

    float bias[4];
    #pragma unroll
    for (int i = 0; i < 4; ++i) {
        int n = n_base + tn + i;
        bias[i] = b1[n] + (b2 ? b2[n] : 0.0f);
    }
    #pragma unroll
    for (int mi = 0; mi < 4; ++mi) {
        float4 o;
        o.x = acc[mi][0] + bias[0];
        o.y = acc[mi][1] + bias[1];
        o.z = acc[mi][2] + bias[2];
        o.w = acc[mi][3] + bias[3];
        *reinterpret_cast<float4*>(C + (size_t)(m_base + tm + mi) * N + n_base + tn) = o;
    }
}

// ---------------------------------------------------------------------------
__global__ __launch_bounds__(512)
void bn_stats_kernel(const float* __restrict__ Z,       // (T,128)
                     const float* __restrict__ gamma,
                     const float* __restrict__ beta,
                     float* __restrict__ scale,
                     float* __restrict__ shift)
{
    const int tid = threadIdx.x;
    const int col = tid & 127;
    const int seg = tid >> 7;     // 0..3
    float s = 0.f, sq = 0.f;
    for (int t = seg * 512; t < (seg + 1) * 512; ++t) {
        float v = Z[(size_t)t * 128 + col];
        s += v;
        sq = fmaf(v, v, sq);
    }
    __shared__ float ps[4][128], pq[4][128];
    ps[seg][col] = s;
    pq[seg][col] = sq;
    __syncthreads();
    if (tid < 128) {
        float sum = ps[0][tid] + ps[1][tid] + ps[2][tid] + ps[3][tid];
        float sqq = pq[0][tid] + pq[1][tid] + pq[2][tid] + pq[3][tid];
        float mean = sum * (1.0f / 2048.0f);
        float var  = sqq * (1.0f / 2048.0f) - mean * mean;
        float sc = gamma[tid] * rsqrtf(var + 1e-5f);
        scale[tid] = sc;
        shift[tid] = beta[tid] - mean * sc;
    }
}

// ---------------------------------------------------------------------------
__global__ __launch_bounds__(512)
void fc2_kernel(const float* __restrict__ Z,      // (T,128)
                const float* __restrict__ scale,
                const float* __restrict__ shift,
                const float* __restrict__ fc2_w,  // (8,128)
                const float* __restrict__ fc2_b,
                float* __restrict__ out)          // (T,8)
{
    const int gid = blockIdx.x * blockDim.x + threadIdx.x;   // 0..16383
    const int o = gid & 7;
    const int t = gid >> 3;

    __shared__ float w_s[8][132];
    __shared__ float sc_s[128], sh_s[128];
    for (int i = threadIdx.x; i < 1024; i += 512) w_s[i >> 7][i & 127] = fc2_w[i];
    if (threadIdx.x < 128) {
        sc_s[threadIdx.x] = scale[threadIdx.x];
        sh_s[threadIdx.x] = shift[threadIdx.x];
    }
    __syncthreads();

    float acc = fc2_b[o];
    const float* zrow = Z + (size_t)t * 128;
    #pragma unroll 4
    for (int k = 0; k < 128; ++k) {
        float zn = fmaf(zrow[k], sc_s[k], sh_s[k]);
        zn = fmaxf(zn, 0.0f);
        acc = fmaf(zn, w_s[o][k], acc);
    }
    out[gid] = acc;
}

// ---------------------------------------------------------------------------
extern "C" void kernel_launch(void* const* d_in, const int* in_sizes, int n_in,
                              void* d_out, int out_size, void* d_ws, size_t ws_size,
                              hipStream_t stream)
{
    const float* x     = (const float*)d_in[0];   // (2048,128,1)
    const float* Wih0  = (const float*)d_in[1];   // (512,1)
    const float* Whh0  = (const float*)d_in[2];   // (512,128)
    const float* bih0  = (const float*)d_in[3];
    const float* bhh0  = (const float*)d_in[4];
    const float* Wih1  = (const float*)d_in[5];   // (512,128)
    const float* Whh1  = (const float*)d_in[6];   // (512,128)
    const float* bih1  = (const float*)d_in[7];
    const float* bhh1  = (const float*)d_in[8];
    const float* fc1_w = (const float*)d_in[9];   // (128,128)
    const float* fc1_b = (const float*)d_in[10];
    const float* gamma = (const float*)d_in[11];
    const float* beta  = (const float*)d_in[12];
    const float* fc2_w = (const float*)d_in[13];  // (8,128)
    const float* fc2_b = (const float*)d_in[14];
    float* out = (float*)d_out;                    // (2048,8) fp32

    unsigned int* flags = (unsigned int*)d_ws;                    // 128 u32 (pad 1 KB)
    _Float16* h1h  = (_Float16*)((char*)d_ws + 1024);             // 2048*128 f16
    float*    h2   = (float*)((char*)d_ws + 1024 + T_STEPS * HID * 2);
    float*    z    = h2 + T_STEPS * HID;
    float*    scale= z  + T_STEPS * HID;
    float*    shift= scale + 128;

    // reset chunk flags each launch (graph-capturable stream op)
    hipMemsetAsync(flags, 0, 1024, stream);

    // K1: 2-CU layer pipeline (block 0 = L0, block 1 = L1 + on-chip G)
    lstm_pipe<<<2, 256, 0, stream>>>(Whh0, Whh1, Wih1, x, Wih0,
                                     bih0, bhh0, bih1, bhh1,
                                     flags, h1h, h2);

    // K4a: z = h2 @ fc1^T + fc1_b
    dim3 g4(T_STEPS / BM, HID / BN);
    gemm_bias_kernel<<<g4, 256, 0, stream>>>(h2, fc1_w, fc1_b, nullptr, z, T_STEPS, HID);

    // K4b: batchnorm stats over T axis
    bn_stats_kernel<<<1, 512, 0, stream>>>(z, gamma, beta, scale, shift);

    // K4c: normalize + relu + fc2
    fc2_kernel<<<T_STEPS * 8 / 512, 512, 0, stream>>>(z, scale, shift, fc2_w, fc2_b, out);
}

// Round 9
// 2109.984 us; speedup vs baseline: 1.6588x; 1.0564x over previous
//
#include <hip/hip_runtime.h>
#include <math.h>

#define T_STEPS 2048
#define HID     128
#define G4      512   // 4*H
#define CH      16    // pipeline chunk (timesteps)
#define NCHUNK  (T_STEPS / CH)

typedef _Float16 half8 __attribute__((ext_vector_type(8)));
typedef float    f32x4 __attribute__((ext_vector_type(4)));

__device__ __forceinline__ float fast_sig(float x) {
    return __fdividef(1.0f, 1.0f + __expf(-x));
}
__device__ __forceinline__ float fast_tanh(float x) {
    return fmaf(2.0f, __fdividef(1.0f, 1.0f + __expf(-2.0f * x)), -1.0f);
}

// ---------------------------------------------------------------------------
// ROUND 13 == ROUND 12 + one-line correctness fix.
//
// R12 failed absmax 2.59: B2 dropped the L1 bias. R9's G (from
// gemm_bias_kernel) had b1+b2 folded in; R12's B1 computes RAW G = Wih1@h1,
// and B2's `gi += pre_cur[g]` never added bsum4 (loaded but dead). Fix:
// add bsum4 at gate accumulation in B2. Everything else identical to R12:
//
//   B0 (L0):  R9 recurrence; writes h1 (f16) to global; releases flags1[c]
//             after the barrier closing each 16-step chunk (RELEASE/AGENT).
//   B1 (G):   per chunk: acquire flags1[c], stage 4-KB h1 chunk to LDS,
//             G = Wih1 @ h1c as 32 MFMA/wave (full 16-col utilization),
//             store G to global, __syncthreads, release flags2[c].
//   B2 (L1):  R9 L1 structure (G prefetched one step ahead under MFMA)
//             + one flags2 spin per 16-step chunk boundary.
// ---------------------------------------------------------------------------
__global__ __launch_bounds__(256)
void lstm_pipe3(const float* __restrict__ Whh0,   // (512,128)
                const float* __restrict__ Whh1,   // (512,128)
                const float* __restrict__ Wih1,   // (512,128)
                const float* __restrict__ x,      // (2048,128)
                const float* __restrict__ wih0,   // (512,)
                const float* __restrict__ bih0,
                const float* __restrict__ bhh0,
                const float* __restrict__ bih1,
                const float* __restrict__ bhh1,
                unsigned int* __restrict__ flags1, // (128,) zeroed per launch
                unsigned int* __restrict__ flags2, // (128,) zeroed per launch
                _Float16* __restrict__ h1h,        // (2048,128) f16
                float* __restrict__ G,             // (2048,512) f32
                float* __restrict__ hout2)         // (2048,128) f32
{
    const int tid  = threadIdx.x;
    const int wave = tid >> 6;         // 0..3
    const int lane = tid & 63;
    const int quad = lane >> 4;
    const int col  = lane & 15;
    const int bid  = blockIdx.x;       // 0=L0, 1=G-GEMM, 2=L1

    const bool act_lane = (col < 8);
    const int  hh = (col >> 2) & 1;
    const int  rr = col & 3;
    const int  u  = wave * 32 + hh * 16 + quad * 4 + rr;   // hidden unit

    __shared__ __align__(16) _Float16 h16[2][HID];     // broadcast h (dbuf)
    __shared__ __align__(16) _Float16 h1s[CH][136];    // B1: staged h1 chunk
    __shared__ float x_s[T_STEPS];                     // B0: x[t,127] table
    __shared__ char occupancy_pad[70400];              // total = 83456 B ->
                                                       // 1 WG/CU, 512-reg RA
    ((volatile char*)occupancy_pad)[tid] = 0;

    const f32x4 zero4 = {0.f, 0.f, 0.f, 0.f};

    if (bid == 1) {
        // ================= B1: G-GEMM worker =================
        // wfrag[mt][kt]: A-row = (wave*8+mt)*16 + col, k = kt*32 + quad*8
        half8 wfrag[8][4];
        #pragma unroll
        for (int mt = 0; mt < 8; ++mt) {
            const float* row = Wih1 + (size_t)((wave * 8 + mt) * 16 + col) * HID;
            #pragma unroll
            for (int kt = 0; kt < 4; ++kt) {
                const float4* p = reinterpret_cast<const float4*>(row + kt * 32 + quad * 8);
                float4 lo = p[0], hi = p[1];
                half8 h;
                h[0] = (_Float16)lo.x; h[1] = (_Float16)lo.y;
                h[2] = (_Float16)lo.z; h[3] = (_Float16)lo.w;
                h[4] = (_Float16)hi.x; h[5] = (_Float16)hi.y;
                h[6] = (_Float16)hi.z; h[7] = (_Float16)hi.w;
                wfrag[mt][kt] = h;
            }
        }
        #pragma unroll
        for (int mt = 0; mt < 8; ++mt)
            #pragma unroll
            for (int kt = 0; kt < 4; ++kt) asm volatile("" : "+a"(wfrag[mt][kt]));

        for (int c = 0; c < NCHUNK; ++c) {
            if (lane == 0) {
                while (__hip_atomic_load(&flags1[c],
                           __ATOMIC_ACQUIRE, __HIP_MEMORY_SCOPE_AGENT) == 0u)
                    __builtin_amdgcn_s_sleep(8);
            }
            // stage h1 chunk: 256 threads x half8 = 16 rows x 128 f16
            {
                const int row = tid >> 4, c16 = tid & 15;
                half8 v = *reinterpret_cast<const half8*>(
                    h1h + (size_t)(c * CH + row) * HID + c16 * 8);
                *reinterpret_cast<half8*>(&h1s[row][c16 * 8]) = v;
            }
            __syncthreads();
            // G chunk: wave covers gates [wave*128, wave*128+128)
            #pragma unroll
            for (int mt = 0; mt < 8; ++mt) {
                f32x4 ag = zero4;
                #pragma unroll
                for (int kt = 0; kt < 4; ++kt) {
                    half8 bg = *reinterpret_cast<const half8*>(
                        &h1s[col][kt * 32 + quad * 8]);
                    ag = __builtin_amdgcn_mfma_f32_16x16x32_f16(wfrag[mt][kt], bg, ag, 0, 0, 0);
                }
                // D[m = mt*16+quad*4+reg (gate within wave), n = col (timestep)]
                *reinterpret_cast<float4*>(
                    &G[(size_t)(c * CH + col) * G4 + (wave * 8 + mt) * 16 + quad * 4]) =
                    make_float4(ag[0], ag[1], ag[2], ag[3]);
            }
            __syncthreads();   // drains all threads' G stores (vmcnt(0))
            if (tid == 0)
                __hip_atomic_store(&flags2[c], 1u,
                                   __ATOMIC_RELEASE, __HIP_MEMORY_SCOPE_AGENT);
        }
        return;
    }

    // ================= B0 / B2: recurrences (R9 structure) =================
    const bool isL0 = (bid == 0);
    const float* Whh = isL0 ? Whh0 : Whh1;
    half8 afrag[8][4];
    #pragma unroll
    for (int r = 0; r < 8; ++r) {
        const float* row = Whh +
            (size_t)(128 * (r >> 1) + wave * 32 + (r & 1) * 16 + col) * HID;
        #pragma unroll
        for (int kt = 0; kt < 4; ++kt) {
            const float4* p = reinterpret_cast<const float4*>(row + kt * 32 + quad * 8);
            float4 lo = p[0], hi = p[1];
            half8 h;
            h[0] = (_Float16)lo.x; h[1] = (_Float16)lo.y;
            h[2] = (_Float16)lo.z; h[3] = (_Float16)lo.w;
            h[4] = (_Float16)hi.x; h[5] = (_Float16)hi.y;
            h[6] = (_Float16)hi.z; h[7] = (_Float16)hi.w;
            afrag[r][kt] = h;
        }
    }
    #pragma unroll
    for (int r = 0; r < 8; ++r)
        #pragma unroll
        for (int kt = 0; kt < 4; ++kt) asm volatile("" : "+a"(afrag[r][kt]));

    f32x4 bsum4 = {0,0,0,0}, w4 = {0,0,0,0};
    if (act_lane) {
        #pragma unroll
        for (int g = 0; g < 4; ++g) {
            if (isL0) {
                bsum4[g] = bih0[128 * g + u] + bhh0[128 * g + u];
                w4[g]    = wih0[128 * g + u];
            } else {
                bsum4[g] = bih1[128 * g + u] + bhh1[128 * g + u];
            }
        }
    }
    asm volatile("" : "+v"(bsum4), "+v"(w4));

    if (isL0) {
        for (int i = tid; i < T_STEPS; i += 256)
            x_s[i] = x[(size_t)i * HID + HID - 1];
    }

    if (tid < HID) h16[0][tid] = (_Float16)0.0f;
    __syncthreads();

    float c_reg = 0.0f;

    if (isL0) {
        // ---------------- B0: layer-0 ----------------
        for (int t = 0; t < T_STEPS; ++t) {
            half8 b0 = *reinterpret_cast<const half8*>(&h16[t & 1][ 0 + quad * 8]);
            half8 b1 = *reinterpret_cast<const half8*>(&h16[t & 1][32 + quad * 8]);
            half8 b2 = *reinterpret_cast<const half8*>(&h16[t & 1][64 + quad * 8]);
            half8 b3 = *reinterpret_cast<const half8*>(&h16[t & 1][96 + quad * 8]);

            f32x4 acc[8];
            #pragma unroll
            for (int r = 0; r < 8; ++r)
                acc[r] = __builtin_amdgcn_mfma_f32_16x16x32_f16(afrag[r][0], b0, zero4, 0, 0, 0);
            #pragma unroll
            for (int r = 0; r < 8; ++r)
                acc[r] = __builtin_amdgcn_mfma_f32_16x16x32_f16(afrag[r][1], b1, acc[r], 0, 0, 0);
            #pragma unroll
            for (int r = 0; r < 8; ++r)
                acc[r] = __builtin_amdgcn_mfma_f32_16x16x32_f16(afrag[r][2], b2, acc[r], 0, 0, 0);
            #pragma unroll
            for (int r = 0; r < 8; ++r)
                acc[r] = __builtin_amdgcn_mfma_f32_16x16x32_f16(afrag[r][3], b3, acc[r], 0, 0, 0);

            float gi = 0.f, gf = 0.f, gg = 0.f, go = 0.f;
            #pragma unroll
            for (int cs = 0; cs < 8; ++cs) {
                if (col == cs) {
                    const int h2_ = cs >> 2, r2_ = cs & 3;
                    gi = acc[0 + h2_][r2_];
                    gf = acc[2 + h2_][r2_];
                    gg = acc[4 + h2_][r2_];
                    go = acc[6 + h2_][r2_];
                }
            }
            f32x4 pre = bsum4 + w4 * x_s[t];
            gi += pre[0]; gf += pre[1]; gg += pre[2]; go += pre[3];

            const float ai = fast_sig(gi);
            const float af = fast_sig(gf);
            const float ag = fast_tanh(gg);
            const float ao = fast_sig(go);
            c_reg = fmaf(af, c_reg, ai * ag);
            const float h = ao * fast_tanh(c_reg);

            if (act_lane) {
                const _Float16 hf = (_Float16)h;
                h16[(t + 1) & 1][u] = hf;
                h1h[(size_t)t * HID + u] = hf;
            }
            __syncthreads();   // vmcnt(0) drain -> h1h stores in L2

            if ((t & 15) == 15 && tid == 0)
                __hip_atomic_store(&flags1[t >> 4], 1u,
                                   __ATOMIC_RELEASE, __HIP_MEMORY_SCOPE_AGENT);
        }
    } else {
        // ---------------- B2: layer-1 (R9 structure + chunk gate) ----------
        // prologue: wait for G chunk 0, load pre_cur
        if (lane == 0) {
            while (__hip_atomic_load(&flags2[0],
                       __ATOMIC_ACQUIRE, __HIP_MEMORY_SCOPE_AGENT) == 0u)
                __builtin_amdgcn_s_sleep(8);
        }
        f32x4 pre_cur = {0,0,0,0}, pre_nxt = {0,0,0,0};
        if (act_lane) {
            #pragma unroll
            for (int g = 0; g < 4; ++g)
                pre_cur[g] = G[128 * g + u];
        }

        for (int t = 0; t < T_STEPS; ++t) {
            // chunk boundary gate: step t+1 enters chunk cn
            if (((t + 1) & 15) == 0 && (t + 1) < T_STEPS) {
                const int cn = (t + 1) >> 4;
                if (lane == 0) {
                    while (__hip_atomic_load(&flags2[cn],
                               __ATOMIC_ACQUIRE, __HIP_MEMORY_SCOPE_AGENT) == 0u)
                        __builtin_amdgcn_s_sleep(8);
                }
            }

            half8 b0 = *reinterpret_cast<const half8*>(&h16[t & 1][ 0 + quad * 8]);
            half8 b1 = *reinterpret_cast<const half8*>(&h16[t & 1][32 + quad * 8]);
            half8 b2 = *reinterpret_cast<const half8*>(&h16[t & 1][64 + quad * 8]);
            half8 b3 = *reinterpret_cast<const half8*>(&h16[t & 1][96 + quad * 8]);

            // prefetch next step's pre-activation (issued under MFMA)
            const int tn = (t + 1 < T_STEPS) ? t + 1 : t;
            if (act_lane) {
                #pragma unroll
                for (int g = 0; g < 4; ++g)
                    pre_nxt[g] = G[(size_t)tn * G4 + 128 * g + u];
            }
            asm volatile("" : "+v"(pre_nxt));

            f32x4 acc[8];
            #pragma unroll
            for (int r = 0; r < 8; ++r)
                acc[r] = __builtin_amdgcn_mfma_f32_16x16x32_f16(afrag[r][0], b0, zero4, 0, 0, 0);
            #pragma unroll
            for (int r = 0; r < 8; ++r)
                acc[r] = __builtin_amdgcn_mfma_f32_16x16x32_f16(afrag[r][1], b1, acc[r], 0, 0, 0);
            #pragma unroll
            for (int r = 0; r < 8; ++r)
                acc[r] = __builtin_amdgcn_mfma_f32_16x16x32_f16(afrag[r][2], b2, acc[r], 0, 0, 0);
            #pragma unroll
            for (int r = 0; r < 8; ++r)
                acc[r] = __builtin_amdgcn_mfma_f32_16x16x32_f16(afrag[r][3], b3, acc[r], 0, 0, 0);

            float gi = 0.f, gf = 0.f, gg = 0.f, go = 0.f;
            #pragma unroll
            for (int cs = 0; cs < 8; ++cs) {
                if (col == cs) {
                    const int h2_ = cs >> 2, r2_ = cs & 3;
                    gi = acc[0 + h2_][r2_];
                    gf = acc[2 + h2_][r2_];
                    gg = acc[4 + h2_][r2_];
                    go = acc[6 + h2_][r2_];
                }
            }
            // R13 FIX: raw G has no bias (R9's gemm folded b1+b2; B1 does not)
            gi += pre_cur[0] + bsum4[0];
            gf += pre_cur[1] + bsum4[1];
            gg += pre_cur[2] + bsum4[2];
            go += pre_cur[3] + bsum4[3];

            const float ai = fast_sig(gi);
            const float af = fast_sig(gf);
            const float ag = fast_tanh(gg);
            const float ao = fast_sig(go);
            c_reg = fmaf(af, c_reg, ai * ag);
            const float h = ao * fast_tanh(c_reg);

            if (act_lane) {
                h16[(t + 1) & 1][u] = (_Float16)h;
                hout2[(size_t)t * HID + u] = h;
            }
            pre_cur = pre_nxt;
            __syncthreads();
        }
    }
}

// ---------------------------------------------------------------------------
// C[m,n] = sum_k A[m,k] * W[n,k] + b1[n] (+ b2[n])    K = 128 fixed
// ---------------------------------------------------------------------------
#define BM 64
#define BN 64
__global__ __launch_bounds__(256)
void gemm_bias_kernel(const float* __restrict__ A,   // (M,128)
                      const float* __restrict__ W,   // (N,128)
                      const float* __restrict__ b1,
                      const float* __restrict__ b2,  // may be null
                      float* __restrict__ C,         // (M,N)
                      int M, int N)
{
    __shared__ float Al[128][BM + 4];
    __shared__ float Wl[128][BN + 4];
    const int tid    = threadIdx.x;
    const int m_base = blockIdx.x * BM;
    const int n_base = blockIdx.y * BN;

    {
        const int r  = tid >> 2;          // 0..63
        const int kq = (tid & 3) * 32;    // 0,32,64,96
        const float4* srcA = reinterpret_cast<const float4*>(A + (size_t)(m_base + r) * 128 + kq);
        #pragma unroll
        for (int i = 0; i < 8; ++i) {
            float4 v = srcA[i];
            int k = kq + 4 * i;
            Al[k + 0][r] = v.x; Al[k + 1][r] = v.y; Al[k + 2][r] = v.z; Al[k + 3][r] = v.w;
        }
        const float4* srcW = reinterpret_cast<const float4*>(W + (size_t)(n_base + r) * 128 + kq);
        #pragma unroll
        for (int i = 0; i < 8; ++i) {
            float4 v = srcW[i];
            int k = kq + 4 * i;
            Wl[k + 0][r] = v.x; Wl[k + 1][r] = v.y; Wl[k + 2][r] = v.z; Wl[k + 3][r] = v.w;
        }
    }
    __syncthreads();

    const int tm = (tid & 15) * 4;
    const int tn = (tid >> 4) * 4;
    float acc[4][4] = {};
    #pragma unroll 8
    for (int k = 0; k < 128; ++k) {
        float4 av = *reinterpret_cast<const float4*>(&Al[k][tm]);
        float4 wv = *reinterpret_cast<const float4*>(&Wl[k][tn]);
        acc[0][0] = fmaf(av.x, wv.x, acc[0][0]);
        acc[0][1] = fmaf(av.x, wv.y, acc[0][1]);
        acc[0][2] = fmaf(av.x, wv.z, acc[0][2]);
        acc[0][3] = fmaf(av.x, wv.w, acc[0][3]);
        acc[1][0] = fmaf(av.y, wv.x, acc[1][0]);
        acc[1][1] = fmaf(av.y, wv.y, acc[1][1]);
        acc[1][2] = fmaf(av.y, wv.z, acc[1][2]);
        acc[1][3] = fmaf(av.y, wv.w, acc[1][3]);
        acc[2][0] = fmaf(av.z, wv.x, acc[2][0]);
        acc[2][1] = fmaf(av.z, wv.y, acc[2][1]);
        acc[2][2] = fmaf(av.z, wv.z, acc[2][2]);
        acc[2][3] = fmaf(av.z, wv.w, acc[2][3]);
        acc[3][0] = fmaf(av.w, wv.x, acc[3][0]);
        acc[3][1] = fmaf(av.w, wv.y, acc[3][1]);
        acc[3][2] = fmaf(av.w, wv.z, acc[3][2]);
        acc[3][3] = fmaf(av.w, wv.w, acc[3][3]);
    }

    float bias[4];
    #pragma unroll
    for (int i = 0; i < 4; ++i) {
        int n = n_base + tn + i;
        bias[i] = b1[n] + (b2 ? b2[n] : 0.0f);
    }
    #pragma unroll
    for (int mi = 0; mi < 4; ++mi) {
        float4 o;
        o.x = acc[mi][0] + bias[0];
        o.y = acc[mi][1] + bias[1];
        o.z = acc[mi][2] + bias[2];
        o.w = acc[mi][3] + bias[3];
        *reinterpret_cast<float4*>(C + (size_t)(m_base + tm + mi) * N + n_base + tn) = o;
    }
}

// ---------------------------------------------------------------------------
__global__ __launch_bounds__(512)
void bn_stats_kernel(const float* __restrict__ Z,       // (T,128)
                     const float* __restrict__ gamma,
                     const float* __restrict__ beta,
                     float* __restrict__ scale,
                     float* __restrict__ shift)
{
    const int tid = threadIdx.x;
    const int col = tid & 127;
    const int seg = tid >> 7;     // 0..3
    float s = 0.f, sq = 0.f;
    for (int t = seg * 512; t < (seg + 1) * 512; ++t) {
        float v = Z[(size_t)t * 128 + col];
        s += v;
        sq = fmaf(v, v, sq);
    }
    __shared__ float ps[4][128], pq[4][128];
    ps[seg][col] = s;
    pq[seg][col] = sq;
    __syncthreads();
    if (tid < 128) {
        float sum = ps[0][tid] + ps[1][tid] + ps[2][tid] + ps[3][tid];
        float sqq = pq[0][tid] + pq[1][tid] + pq[2][tid] + pq[3][tid];
        float mean = sum * (1.0f / 2048.0f);
        float var  = sqq * (1.0f / 2048.0f) - mean * mean;
        float sc = gamma[tid] * rsqrtf(var + 1e-5f);
        scale[tid] = sc;
        shift[tid] = beta[tid] - mean * sc;
    }
}

// ---------------------------------------------------------------------------
__global__ __launch_bounds__(512)
void fc2_kernel(const float* __restrict__ Z,      // (T,128)
                const float* __restrict__ scale,
                const float* __restrict__ shift,
                const float* __restrict__ fc2_w,  // (8,128)
                const float* __restrict__ fc2_b,
                float* __restrict__ out)          // (T,8)
{
    const int gid = blockIdx.x * blockDim.x + threadIdx.x;   // 0..16383
    const int o = gid & 7;
    const int t = gid >> 3;

    __shared__ float w_s[8][132];
    __shared__ float sc_s[128], sh_s[128];
    for (int i = threadIdx.x; i < 1024; i += 512) w_s[i >> 7][i & 127] = fc2_w[i];
    if (threadIdx.x < 128) {
        sc_s[threadIdx.x] = scale[threadIdx.x];
        sh_s[threadIdx.x] = shift[threadIdx.x];
    }
    __syncthreads();

    float acc = fc2_b[o];
    const float* zrow = Z + (size_t)t * 128;
    #pragma unroll 4
    for (int k = 0; k < 128; ++k) {
        float zn = fmaf(zrow[k], sc_s[k], sh_s[k]);
        zn = fmaxf(zn, 0.0f);
        acc = fmaf(zn, w_s[o][k], acc);
    }
    out[gid] = acc;
}

// ---------------------------------------------------------------------------
extern "C" void kernel_launch(void* const* d_in, const int* in_sizes, int n_in,
                              void* d_out, int out_size, void* d_ws, size_t ws_size,
                              hipStream_t stream)
{
    const float* x     = (const float*)d_in[0];   // (2048,128,1)
    const float* Wih0  = (const float*)d_in[1];   // (512,1)
    const float* Whh0  = (const float*)d_in[2];   // (512,128)
    const float* bih0  = (const float*)d_in[3];
    const float* bhh0  = (const float*)d_in[4];
    const float* Wih1  = (const float*)d_in[5];   // (512,128)
    const float* Whh1  = (const float*)d_in[6];   // (512,128)
    const float* bih1  = (const float*)d_in[7];
    const float* bhh1  = (const float*)d_in[8];
    const float* fc1_w = (const float*)d_in[9];   // (128,128)
    const float* fc1_b = (const float*)d_in[10];
    const float* gamma = (const float*)d_in[11];
    const float* beta  = (const float*)d_in[12];
    const float* fc2_w = (const float*)d_in[13];  // (8,128)
    const float* fc2_b = (const float*)d_in[14];
    float* out = (float*)d_out;                    // (2048,8) fp32

    unsigned int* flags1 = (unsigned int*)d_ws;                   // 128 u32
    unsigned int* flags2 = flags1 + 256;                          // 128 u32
    _Float16* h1h  = (_Float16*)((char*)d_ws + 2048);             // 2048*128 f16
    float*    G    = (float*)((char*)d_ws + 2048 + T_STEPS * HID * 2);  // 2048*512
    float*    h2   = G + (size_t)T_STEPS * G4;
    float*    z    = h2 + T_STEPS * HID;
    float*    scale= z  + T_STEPS * HID;
    float*    shift= scale + 128;

    // reset chunk flags each launch (graph-capturable stream op)
    hipMemsetAsync(flags1, 0, 2048, stream);

    // K1: 3-CU pipeline (B0 = L0, B1 = G-GEMM, B2 = L1)
    lstm_pipe3<<<3, 256, 0, stream>>>(Whh0, Whh1, Wih1, x, Wih0,
                                      bih0, bhh0, bih1, bhh1,
                                      flags1, flags2, h1h, G, h2);

    // K4a: z = h2 @ fc1^T + fc1_b
    dim3 g4(T_STEPS / BM, HID / BN);
    gemm_bias_kernel<<<g4, 256, 0, stream>>>(h2, fc1_w, fc1_b, nullptr, z, T_STEPS, HID);

    // K4b: batchnorm stats over T axis
    bn_stats_kernel<<<1, 512, 0, stream>>>(z, gamma, beta, scale, shift);

    // K4c: normalize + relu + fc2
    fc2_kernel<<<T_STEPS * 8 / 512, 512, 0, stream>>>(z, scale, shift, fc2_w, fc2_b, out);
}

// Round 10
// 1873.271 us; speedup vs baseline: 1.8684x; 1.1264x over previous
//
#include <hip/hip_runtime.h>
#include <math.h>

#define T_STEPS 2048
#define HID     128
#define G4      512   // 4*H
#define CH      16    // pipeline chunk (timesteps)
#define NCHUNK  (T_STEPS / CH)

typedef _Float16 half8 __attribute__((ext_vector_type(8)));
typedef float    f32x4 __attribute__((ext_vector_type(4)));

__device__ __forceinline__ float fast_sig(float x) {
    return __fdividef(1.0f, 1.0f + __expf(-x));
}
__device__ __forceinline__ float fast_tanh(float x) {
    return fmaf(2.0f, __fdividef(1.0f, 1.0f + __expf(-2.0f * x)), -1.0f);
}

// ---------------------------------------------------------------------------
// ROUND 14 == ROUND 13 + latency fixes (isolated A/B on the G-latency theory).
//
// R13 results: 2229->2110 us, pipe at 1016 ns/step vs R9's 930 ns floor.
// Counters: WRITE 5640 KB == G(4096)+h1h(512)+h2(1024) -> G round-trips HBM
// (cross-XCD); FETCH shows ~1 MB of G reads from HBM. B2's depth-1 prefetch
// leaves ~500 cy of HBM latency exposed at every step's vmcnt(0) barrier
// drain. Plus s_sleep(8)=512cy overshoot per gate (128 gates x 2 blocks).
//
// Changes vs R13 (nothing else):
//   1. B2 prefetches G two steps ahead (issue G[t+2] at step t -> a full
//      ~2200-cy step to cover ~900-cy HBM latency). Chunk gate moves to
//      where t+2 crosses a 16-step boundary.
//   2. s_sleep(8) -> s_sleep(1) in all spins.
//
// Structure (unchanged):
//   B0 (L0):  R9 recurrence; h1 (f16) to global; releases flags1[c]/chunk.
//   B1 (G):   per chunk: acquire flags1[c], stage h1 chunk to LDS,
//             G = Wih1 @ h1c (32 MFMA/wave, full 16-col), store G,
//             __syncthreads, release flags2[c].
//   B2 (L1):  R9 L1 + bsum4 bias + depth-2 G prefetch + chunk gate.
// ---------------------------------------------------------------------------
__global__ __launch_bounds__(256)
void lstm_pipe3(const float* __restrict__ Whh0,   // (512,128)
                const float* __restrict__ Whh1,   // (512,128)
                const float* __restrict__ Wih1,   // (512,128)
                const float* __restrict__ x,      // (2048,128)
                const float* __restrict__ wih0,   // (512,)
                const float* __restrict__ bih0,
                const float* __restrict__ bhh0,
                const float* __restrict__ bih1,
                const float* __restrict__ bhh1,
                unsigned int* __restrict__ flags1, // (128,) zeroed per launch
                unsigned int* __restrict__ flags2, // (128,) zeroed per launch
                _Float16* __restrict__ h1h,        // (2048,128) f16
                float* __restrict__ G,             // (2048,512) f32
                float* __restrict__ hout2)         // (2048,128) f32
{
    const int tid  = threadIdx.x;
    const int wave = tid >> 6;         // 0..3
    const int lane = tid & 63;
    const int quad = lane >> 4;
    const int col  = lane & 15;
    const int bid  = blockIdx.x;       // 0=L0, 1=G-GEMM, 2=L1

    const bool act_lane = (col < 8);
    const int  hh = (col >> 2) & 1;
    const int  rr = col & 3;
    const int  u  = wave * 32 + hh * 16 + quad * 4 + rr;   // hidden unit

    __shared__ __align__(16) _Float16 h16[2][HID];     // broadcast h (dbuf)
    __shared__ __align__(16) _Float16 h1s[CH][136];    // B1: staged h1 chunk
    __shared__ float x_s[T_STEPS];                     // B0: x[t,127] table
    __shared__ char occupancy_pad[70400];              // total = 83456 B ->
                                                       // 1 WG/CU, 512-reg RA
    ((volatile char*)occupancy_pad)[tid] = 0;

    const f32x4 zero4 = {0.f, 0.f, 0.f, 0.f};

    if (bid == 1) {
        // ================= B1: G-GEMM worker =================
        // wfrag[mt][kt]: A-row = (wave*8+mt)*16 + col, k = kt*32 + quad*8
        half8 wfrag[8][4];
        #pragma unroll
        for (int mt = 0; mt < 8; ++mt) {
            const float* row = Wih1 + (size_t)((wave * 8 + mt) * 16 + col) * HID;
            #pragma unroll
            for (int kt = 0; kt < 4; ++kt) {
                const float4* p = reinterpret_cast<const float4*>(row + kt * 32 + quad * 8);
                float4 lo = p[0], hi = p[1];
                half8 h;
                h[0] = (_Float16)lo.x; h[1] = (_Float16)lo.y;
                h[2] = (_Float16)lo.z; h[3] = (_Float16)lo.w;
                h[4] = (_Float16)hi.x; h[5] = (_Float16)hi.y;
                h[6] = (_Float16)hi.z; h[7] = (_Float16)hi.w;
                wfrag[mt][kt] = h;
            }
        }
        #pragma unroll
        for (int mt = 0; mt < 8; ++mt)
            #pragma unroll
            for (int kt = 0; kt < 4; ++kt) asm volatile("" : "+a"(wfrag[mt][kt]));

        for (int c = 0; c < NCHUNK; ++c) {
            if (lane == 0) {
                while (__hip_atomic_load(&flags1[c],
                           __ATOMIC_ACQUIRE, __HIP_MEMORY_SCOPE_AGENT) == 0u)
                    __builtin_amdgcn_s_sleep(1);
            }
            // stage h1 chunk: 256 threads x half8 = 16 rows x 128 f16
            {
                const int row = tid >> 4, c16 = tid & 15;
                half8 v = *reinterpret_cast<const half8*>(
                    h1h + (size_t)(c * CH + row) * HID + c16 * 8);
                *reinterpret_cast<half8*>(&h1s[row][c16 * 8]) = v;
            }
            __syncthreads();
            // G chunk: wave covers gates [wave*128, wave*128+128)
            #pragma unroll
            for (int mt = 0; mt < 8; ++mt) {
                f32x4 ag = zero4;
                #pragma unroll
                for (int kt = 0; kt < 4; ++kt) {
                    half8 bg = *reinterpret_cast<const half8*>(
                        &h1s[col][kt * 32 + quad * 8]);
                    ag = __builtin_amdgcn_mfma_f32_16x16x32_f16(wfrag[mt][kt], bg, ag, 0, 0, 0);
                }
                // D[m = mt*16+quad*4+reg (gate within wave), n = col (timestep)]
                *reinterpret_cast<float4*>(
                    &G[(size_t)(c * CH + col) * G4 + (wave * 8 + mt) * 16 + quad * 4]) =
                    make_float4(ag[0], ag[1], ag[2], ag[3]);
            }
            __syncthreads();   // drains all threads' G stores (vmcnt(0))
            if (tid == 0)
                __hip_atomic_store(&flags2[c], 1u,
                                   __ATOMIC_RELEASE, __HIP_MEMORY_SCOPE_AGENT);
        }
        return;
    }

    // ================= B0 / B2: recurrences (R9 structure) =================
    const bool isL0 = (bid == 0);
    const float* Whh = isL0 ? Whh0 : Whh1;
    half8 afrag[8][4];
    #pragma unroll
    for (int r = 0; r < 8; ++r) {
        const float* row = Whh +
            (size_t)(128 * (r >> 1) + wave * 32 + (r & 1) * 16 + col) * HID;
        #pragma unroll
        for (int kt = 0; kt < 4; ++kt) {
            const float4* p = reinterpret_cast<const float4*>(row + kt * 32 + quad * 8);
            float4 lo = p[0], hi = p[1];
            half8 h;
            h[0] = (_Float16)lo.x; h[1] = (_Float16)lo.y;
            h[2] = (_Float16)lo.z; h[3] = (_Float16)lo.w;
            h[4] = (_Float16)hi.x; h[5] = (_Float16)hi.y;
            h[6] = (_Float16)hi.z; h[7] = (_Float16)hi.w;
            afrag[r][kt] = h;
        }
    }
    #pragma unroll
    for (int r = 0; r < 8; ++r)
        #pragma unroll
        for (int kt = 0; kt < 4; ++kt) asm volatile("" : "+a"(afrag[r][kt]));

    f32x4 bsum4 = {0,0,0,0}, w4 = {0,0,0,0};
    if (act_lane) {
        #pragma unroll
        for (int g = 0; g < 4; ++g) {
            if (isL0) {
                bsum4[g] = bih0[128 * g + u] + bhh0[128 * g + u];
                w4[g]    = wih0[128 * g + u];
            } else {
                bsum4[g] = bih1[128 * g + u] + bhh1[128 * g + u];
            }
        }
    }
    asm volatile("" : "+v"(bsum4), "+v"(w4));

    if (isL0) {
        for (int i = tid; i < T_STEPS; i += 256)
            x_s[i] = x[(size_t)i * HID + HID - 1];
    }

    if (tid < HID) h16[0][tid] = (_Float16)0.0f;
    __syncthreads();

    float c_reg = 0.0f;

    if (isL0) {
        // ---------------- B0: layer-0 ----------------
        for (int t = 0; t < T_STEPS; ++t) {
            half8 b0 = *reinterpret_cast<const half8*>(&h16[t & 1][ 0 + quad * 8]);
            half8 b1 = *reinterpret_cast<const half8*>(&h16[t & 1][32 + quad * 8]);
            half8 b2 = *reinterpret_cast<const half8*>(&h16[t & 1][64 + quad * 8]);
            half8 b3 = *reinterpret_cast<const half8*>(&h16[t & 1][96 + quad * 8]);

            f32x4 acc[8];
            #pragma unroll
            for (int r = 0; r < 8; ++r)
                acc[r] = __builtin_amdgcn_mfma_f32_16x16x32_f16(afrag[r][0], b0, zero4, 0, 0, 0);
            #pragma unroll
            for (int r = 0; r < 8; ++r)
                acc[r] = __builtin_amdgcn_mfma_f32_16x16x32_f16(afrag[r][1], b1, acc[r], 0, 0, 0);
            #pragma unroll
            for (int r = 0; r < 8; ++r)
                acc[r] = __builtin_amdgcn_mfma_f32_16x16x32_f16(afrag[r][2], b2, acc[r], 0, 0, 0);
            #pragma unroll
            for (int r = 0; r < 8; ++r)
                acc[r] = __builtin_amdgcn_mfma_f32_16x16x32_f16(afrag[r][3], b3, acc[r], 0, 0, 0);

            float gi = 0.f, gf = 0.f, gg = 0.f, go = 0.f;
            #pragma unroll
            for (int cs = 0; cs < 8; ++cs) {
                if (col == cs) {
                    const int h2_ = cs >> 2, r2_ = cs & 3;
                    gi = acc[0 + h2_][r2_];
                    gf = acc[2 + h2_][r2_];
                    gg = acc[4 + h2_][r2_];
                    go = acc[6 + h2_][r2_];
                }
            }
            f32x4 pre = bsum4 + w4 * x_s[t];
            gi += pre[0]; gf += pre[1]; gg += pre[2]; go += pre[3];

            const float ai = fast_sig(gi);
            const float af = fast_sig(gf);
            const float ag = fast_tanh(gg);
            const float ao = fast_sig(go);
            c_reg = fmaf(af, c_reg, ai * ag);
            const float h = ao * fast_tanh(c_reg);

            if (act_lane) {
                const _Float16 hf = (_Float16)h;
                h16[(t + 1) & 1][u] = hf;
                h1h[(size_t)t * HID + u] = hf;
            }
            __syncthreads();   // vmcnt(0) drain -> h1h stores in L2

            if ((t & 15) == 15 && tid == 0)
                __hip_atomic_store(&flags1[t >> 4], 1u,
                                   __ATOMIC_RELEASE, __HIP_MEMORY_SCOPE_AGENT);
        }
    } else {
        // ---------------- B2: layer-1 (depth-2 G prefetch) ----------------
        // prologue: wait for G chunk 0, preload pre for steps 0 and 1
        if (lane == 0) {
            while (__hip_atomic_load(&flags2[0],
                       __ATOMIC_ACQUIRE, __HIP_MEMORY_SCOPE_AGENT) == 0u)
                __builtin_amdgcn_s_sleep(1);
        }
        f32x4 pre_cur = {0,0,0,0}, pre_nxt = {0,0,0,0}, pre_fut = {0,0,0,0};
        if (act_lane) {
            #pragma unroll
            for (int g = 0; g < 4; ++g) {
                pre_cur[g] = G[128 * g + u];             // G[0]
                pre_nxt[g] = G[(size_t)G4 + 128 * g + u]; // G[1]
            }
        }

        for (int t = 0; t < T_STEPS; ++t) {
            // gate for the chunk containing t+2 (the prefetch target)
            const int tp = t + 2;
            if (tp < T_STEPS && (tp & 15) == 0) {
                const int cn = tp >> 4;
                if (lane == 0) {
                    while (__hip_atomic_load(&flags2[cn],
                               __ATOMIC_ACQUIRE, __HIP_MEMORY_SCOPE_AGENT) == 0u)
                        __builtin_amdgcn_s_sleep(1);
                }
            }
            const int tf = (tp < T_STEPS) ? tp : T_STEPS - 1;

            half8 b0 = *reinterpret_cast<const half8*>(&h16[t & 1][ 0 + quad * 8]);
            half8 b1 = *reinterpret_cast<const half8*>(&h16[t & 1][32 + quad * 8]);
            half8 b2 = *reinterpret_cast<const half8*>(&h16[t & 1][64 + quad * 8]);
            half8 b3 = *reinterpret_cast<const half8*>(&h16[t & 1][96 + quad * 8]);

            // depth-2 prefetch: issue G[t+2] now; consumed two barriers later
            if (act_lane) {
                #pragma unroll
                for (int g = 0; g < 4; ++g)
                    pre_fut[g] = G[(size_t)tf * G4 + 128 * g + u];
            }
            asm volatile("" : "+v"(pre_fut));

            f32x4 acc[8];
            #pragma unroll
            for (int r = 0; r < 8; ++r)
                acc[r] = __builtin_amdgcn_mfma_f32_16x16x32_f16(afrag[r][0], b0, zero4, 0, 0, 0);
            #pragma unroll
            for (int r = 0; r < 8; ++r)
                acc[r] = __builtin_amdgcn_mfma_f32_16x16x32_f16(afrag[r][1], b1, acc[r], 0, 0, 0);
            #pragma unroll
            for (int r = 0; r < 8; ++r)
                acc[r] = __builtin_amdgcn_mfma_f32_16x16x32_f16(afrag[r][2], b2, acc[r], 0, 0, 0);
            #pragma unroll
            for (int r = 0; r < 8; ++r)
                acc[r] = __builtin_amdgcn_mfma_f32_16x16x32_f16(afrag[r][3], b3, acc[r], 0, 0, 0);

            float gi = 0.f, gf = 0.f, gg = 0.f, go = 0.f;
            #pragma unroll
            for (int cs = 0; cs < 8; ++cs) {
                if (col == cs) {
                    const int h2_ = cs >> 2, r2_ = cs & 3;
                    gi = acc[0 + h2_][r2_];
                    gf = acc[2 + h2_][r2_];
                    gg = acc[4 + h2_][r2_];
                    go = acc[6 + h2_][r2_];
                }
            }
            // raw G has no bias (B1 computes Wih1@h1 only)
            gi += pre_cur[0] + bsum4[0];
            gf += pre_cur[1] + bsum4[1];
            gg += pre_cur[2] + bsum4[2];
            go += pre_cur[3] + bsum4[3];

            const float ai = fast_sig(gi);
            const float af = fast_sig(gf);
            const float ag = fast_tanh(gg);
            const float ao = fast_sig(go);
            c_reg = fmaf(af, c_reg, ai * ag);
            const float h = ao * fast_tanh(c_reg);

            if (act_lane) {
                h16[(t + 1) & 1][u] = (_Float16)h;
                hout2[(size_t)t * HID + u] = h;
            }
            pre_cur = pre_nxt;
            pre_nxt = pre_fut;
            __syncthreads();
        }
    }
}

// ---------------------------------------------------------------------------
// C[m,n] = sum_k A[m,k] * W[n,k] + b1[n] (+ b2[n])    K = 128 fixed
// ---------------------------------------------------------------------------
#define BM 64
#define BN 64
__global__ __launch_bounds__(256)
void gemm_bias_kernel(const float* __restrict__ A,   // (M,128)
                      const float* __restrict__ W,   // (N,128)
                      const float* __restrict__ b1,
                      const float* __restrict__ b2,  // may be null
                      float* __restrict__ C,         // (M,N)
                      int M, int N)
{
    __shared__ float Al[128][BM + 4];
    __shared__ float Wl[128][BN + 4];
    const int tid    = threadIdx.x;
    const int m_base = blockIdx.x * BM;
    const int n_base = blockIdx.y * BN;

    {
        const int r  = tid >> 2;          // 0..63
        const int kq = (tid & 3) * 32;    // 0,32,64,96
        const float4* srcA = reinterpret_cast<const float4*>(A + (size_t)(m_base + r) * 128 + kq);
        #pragma unroll
        for (int i = 0; i < 8; ++i) {
            float4 v = srcA[i];
            int k = kq + 4 * i;
            Al[k + 0][r] = v.x; Al[k + 1][r] = v.y; Al[k + 2][r] = v.z; Al[k + 3][r] = v.w;
        }
        const float4* srcW = reinterpret_cast<const float4*>(W + (size_t)(n_base + r) * 128 + kq);
        #pragma unroll
        for (int i = 0; i < 8; ++i) {
            float4 v = srcW[i];
            int k = kq + 4 * i;
            Wl[k + 0][r] = v.x; Wl[k + 1][r] = v.y; Wl[k + 2][r] = v.z; Wl[k + 3][r] = v.w;
        }
    }
    __syncthreads();

    const int tm = (tid & 15) * 4;
    const int tn = (tid >> 4) * 4;
    float acc[4][4] = {};
    #pragma unroll 8
    for (int k = 0; k < 128; ++k) {
        float4 av = *reinterpret_cast<const float4*>(&Al[k][tm]);
        float4 wv = *reinterpret_cast<const float4*>(&Wl[k][tn]);
        acc[0][0] = fmaf(av.x, wv.x, acc[0][0]);
        acc[0][1] = fmaf(av.x, wv.y, acc[0][1]);
        acc[0][2] = fmaf(av.x, wv.z, acc[0][2]);
        acc[0][3] = fmaf(av.x, wv.w, acc[0][3]);
        acc[1][0] = fmaf(av.y, wv.x, acc[1][0]);
        acc[1][1] = fmaf(av.y, wv.y, acc[1][1]);
        acc[1][2] = fmaf(av.y, wv.z, acc[1][2]);
        acc[1][3] = fmaf(av.y, wv.w, acc[1][3]);
        acc[2][0] = fmaf(av.z, wv.x, acc[2][0]);
        acc[2][1] = fmaf(av.z, wv.y, acc[2][1]);
        acc[2][2] = fmaf(av.z, wv.z, acc[2][2]);
        acc[2][3] = fmaf(av.z, wv.w, acc[2][3]);
        acc[3][0] = fmaf(av.w, wv.x, acc[3][0]);
        acc[3][1] = fmaf(av.w, wv.y, acc[3][1]);
        acc[3][2] = fmaf(av.w, wv.z, acc[3][2]);
        acc[3][3] = fmaf(av.w, wv.w, acc[3][3]);
    }

    float bias[4];
    #pragma unroll
    for (int i = 0; i < 4; ++i) {
        int n = n_base + tn + i;
        bias[i] = b1[n] + (b2 ? b2[n] : 0.0f);
    }
    #pragma unroll
    for (int mi = 0; mi < 4; ++mi) {
        float4 o;
        o.x = acc[mi][0] + bias[0];
        o.y = acc[mi][1] + bias[1];
        o.z = acc[mi][2] + bias[2];
        o.w = acc[mi][3] + bias[3];
        *reinterpret_cast<float4*>(C + (size_t)(m_base + tm + mi) * N + n_base + tn) = o;
    }
}

// ---------------------------------------------------------------------------
__global__ __launch_bounds__(512)
void bn_stats_kernel(const float* __restrict__ Z,       // (T,128)
                     const float* __restrict__ gamma,
                     const float* __restrict__ beta,
                     float* __restrict__ scale,
                     float* __restrict__ shift)
{
    const int tid = threadIdx.x;
    const int col = tid & 127;
    const int seg = tid >> 7;     // 0..3
    float s = 0.f, sq = 0.f;
    for (int t = seg * 512; t < (seg + 1) * 512; ++t) {
        float v = Z[(size_t)t * 128 + col];
        s += v;
        sq = fmaf(v, v, sq);
    }
    __shared__ float ps[4][128], pq[4][128];
    ps[seg][col] = s;
    pq[seg][col] = sq;
    __syncthreads();
    if (tid < 128) {
        float sum = ps[0][tid] + ps[1][tid] + ps[2][tid] + ps[3][tid];
        float sqq = pq[0][tid] + pq[1][tid] + pq[2][tid] + pq[3][tid];
        float mean = sum * (1.0f / 2048.0f);
        float var  = sqq * (1.0f / 2048.0f) - mean * mean;
        float sc = gamma[tid] * rsqrtf(var + 1e-5f);
        scale[tid] = sc;
        shift[tid] = beta[tid] - mean * sc;
    }
}

// ---------------------------------------------------------------------------
__global__ __launch_bounds__(512)
void fc2_kernel(const float* __restrict__ Z,      // (T,128)
                const float* __restrict__ scale,
                const float* __restrict__ shift,
                const float* __restrict__ fc2_w,  // (8,128)
                const float* __restrict__ fc2_b,
                float* __restrict__ out)          // (T,8)
{
    const int gid = blockIdx.x * blockDim.x + threadIdx.x;   // 0..16383
    const int o = gid & 7;
    const int t = gid >> 3;

    __shared__ float w_s[8][132];
    __shared__ float sc_s[128], sh_s[128];
    for (int i = threadIdx.x; i < 1024; i += 512) w_s[i >> 7][i & 127] = fc2_w[i];
    if (threadIdx.x < 128) {
        sc_s[threadIdx.x] = scale[threadIdx.x];
        sh_s[threadIdx.x] = shift[threadIdx.x];
    }
    __syncthreads();

    float acc = fc2_b[o];
    const float* zrow = Z + (size_t)t * 128;
    #pragma unroll 4
    for (int k = 0; k < 128; ++k) {
        float zn = fmaf(zrow[k], sc_s[k], sh_s[k]);
        zn = fmaxf(zn, 0.0f);
        acc = fmaf(zn, w_s[o][k], acc);
    }
    out[gid] = acc;
}

// ---------------------------------------------------------------------------
extern "C" void kernel_launch(void* const* d_in, const int* in_sizes, int n_in,
                              void* d_out, int out_size, void* d_ws, size_t ws_size,
                              hipStream_t stream)
{
    const float* x     = (const float*)d_in[0];   // (2048,128,1)
    const float* Wih0  = (const float*)d_in[1];   // (512,1)
    const float* Whh0  = (const float*)d_in[2];   // (512,128)
    const float* bih0  = (const float*)d_in[3];
    const float* bhh0  = (const float*)d_in[4];
    const float* Wih1  = (const float*)d_in[5];   // (512,128)
    const float* Whh1  = (const float*)d_in[6];   // (512,128)
    const float* bih1  = (const float*)d_in[7];
    const float* bhh1  = (const float*)d_in[8];
    const float* fc1_w = (const float*)d_in[9];   // (128,128)
    const float* fc1_b = (const float*)d_in[10];
    const float* gamma = (const float*)d_in[11];
    const float* beta  = (const float*)d_in[12];
    const float* fc2_w = (const float*)d_in[13];  // (8,128)
    const float* fc2_b = (const float*)d_in[14];
    float* out = (float*)d_out;                    // (2048,8) fp32

    unsigned int* flags1 = (unsigned int*)d_ws;                   // 128 u32
    unsigned int* flags2 = flags1 + 256;                          // 128 u32
    _Float16* h1h  = (_Float16*)((char*)d_ws + 2048);             // 2048*128 f16
    float*    G    = (float*)((char*)d_ws + 2048 + T_STEPS * HID * 2);  // 2048*512
    float*    h2   = G + (size_t)T_STEPS * G4;
    float*    z    = h2 + T_STEPS * HID;
    float*    scale= z  + T_STEPS * HID;
    float*    shift= scale + 128;

    // reset chunk flags each launch (graph-capturable stream op)
    hipMemsetAsync(flags1, 0, 2048, stream);

    // K1: 3-CU pipeline (B0 = L0, B1 = G-GEMM, B2 = L1)
    lstm_pipe3<<<3, 256, 0, stream>>>(Whh0, Whh1, Wih1, x, Wih0,
                                      bih0, bhh0, bih1, bhh1,
                                      flags1, flags2, h1h, G, h2);

    // K4a: z = h2 @ fc1^T + fc1_b
    dim3 g4(T_STEPS / BM, HID / BN);
    gemm_bias_kernel<<<g4, 256, 0, stream>>>(h2, fc1_w, fc1_b, nullptr, z, T_STEPS, HID);

    // K4b: batchnorm stats over T axis
    bn_stats_kernel<<<1, 512, 0, stream>>>(z, gamma, beta, scale, shift);

    // K4c: normalize + relu + fc2
    fc2_kernel<<<T_STEPS * 8 / 512, 512, 0, stream>>>(z, scale, shift, fc2_w, fc2_b, out);
}